// Round 4
// baseline (1760.771 us; speedup 1.0000x reference)
//
#include <hip/hip_runtime.h>
#include <hip/hip_bf16.h>

typedef __attribute__((ext_vector_type(8))) short short8;
typedef __attribute__((ext_vector_type(4))) float f32x4;

// ---------------------------------------------------------------------------
// Threefry2x32 (JAX partitionable semantics) + erfinv (XLA f32 polynomial)
// ---------------------------------------------------------------------------
#define TF_ROUND(r) { x0 += x1; x1 = ((x1<<(r))|(x1>>(32-(r)))); x1 ^= x0; }

__device__ __forceinline__ void tf2x32(unsigned k0, unsigned k1, unsigned x0, unsigned x1,
                                       unsigned &o0, unsigned &o1)
{
  unsigned ks2 = k0 ^ k1 ^ 0x1BD11BDAu;
  x0 += k0; x1 += k1;
  TF_ROUND(13) TF_ROUND(15) TF_ROUND(26) TF_ROUND(6)
  x0 += k1;  x1 += ks2 + 1u;
  TF_ROUND(17) TF_ROUND(29) TF_ROUND(16) TF_ROUND(24)
  x0 += ks2; x1 += k0 + 2u;
  TF_ROUND(13) TF_ROUND(15) TF_ROUND(26) TF_ROUND(6)
  x0 += k0;  x1 += k1 + 3u;
  TF_ROUND(17) TF_ROUND(29) TF_ROUND(16) TF_ROUND(24)
  x0 += k1;  x1 += ks2 + 4u;
  TF_ROUND(13) TF_ROUND(15) TF_ROUND(26) TF_ROUND(6)
  x0 += ks2; x1 += k0 + 5u;
  o0 = x0; o1 = x1;
}

__device__ __forceinline__ float erfinv_f(float x)
{
  float w = -log1pf(-x * x);
  float p;
  if (w < 5.0f) {
    w -= 2.5f;
    p = 2.81022636e-08f;
    p = fmaf(p, w, 3.43273939e-07f);
    p = fmaf(p, w, -3.5233877e-06f);
    p = fmaf(p, w, -4.39150654e-06f);
    p = fmaf(p, w, 0.00021858087f);
    p = fmaf(p, w, -0.00125372503f);
    p = fmaf(p, w, -0.00417768164f);
    p = fmaf(p, w, 0.246640727f);
    p = fmaf(p, w, 1.50140941f);
  } else {
    w = sqrtf(w) - 3.0f;
    p = -0.000200214257f;
    p = fmaf(p, w, 0.000100950558f);
    p = fmaf(p, w, 0.00134934322f);
    p = fmaf(p, w, -0.00367342844f);
    p = fmaf(p, w, 0.00573950773f);
    p = fmaf(p, w, -0.0076224613f);
    p = fmaf(p, w, 0.00943887047f);
    p = fmaf(p, w, 1.00167406f);
    p = fmaf(p, w, 2.83297682f);
  }
  return p * x;
}

__device__ __forceinline__ float rng_normal(unsigned b)
{
  float f = __uint_as_float((b >> 9) | 0x3f800000u) - 1.0f;  // [0,1)
  const float lo = -0.99999994f;
  float u = fmaxf(lo, f * 2.0f + lo);
  return 1.41421356f * erfinv_f(u);
}

__device__ __forceinline__ float softplusf(float x) { return log1pf(expf(x)); }

// ---------------------------------------------------------------------------
// DDE (PEConv mean) kernels
// ---------------------------------------------------------------------------
__global__ void dde_count(const int* __restrict__ h, const int* __restrict__ t,
                          float* __restrict__ cnt_t, float* __restrict__ cnt_h, int E)
{
  int e = blockIdx.x * blockDim.x + threadIdx.x;
  if (e >= E) return;
  atomicAdd(&cnt_t[t[e]], 1.0f);
  atomicAdd(&cnt_h[h[e]], 1.0f);
}

__global__ void dde_scatter1(const int* __restrict__ h, const int* __restrict__ t,
                             const float* __restrict__ topic,
                             float* __restrict__ f1, float* __restrict__ g1, int E)
{
  int e = blockIdx.x * blockDim.x + threadIdx.x;
  if (e >= E) return;
  int hh = h[e], tt = t[e];
  atomicAdd(&f1[tt*2+0], topic[hh*2+0]);
  atomicAdd(&f1[tt*2+1], topic[hh*2+1]);
  atomicAdd(&g1[hh*2+0], topic[tt*2+0]);
  atomicAdd(&g1[hh*2+1], topic[tt*2+1]);
}

__global__ void dde_scatter2(const int* __restrict__ h, const int* __restrict__ t,
                             const float* __restrict__ f1, const float* __restrict__ g1,
                             float* __restrict__ f2, float* __restrict__ g2, int E)
{
  int e = blockIdx.x * blockDim.x + threadIdx.x;
  if (e >= E) return;
  int hh = h[e], tt = t[e];
  atomicAdd(&f2[tt*2+0], f1[hh*2+0]);
  atomicAdd(&f2[tt*2+1], f1[hh*2+1]);
  atomicAdd(&g2[hh*2+0], g1[tt*2+0]);
  atomicAdd(&g2[hh*2+1], g1[tt*2+1]);
}

__global__ void dde_norm(float* __restrict__ f, float* __restrict__ g,
                         const float* __restrict__ ct, const float* __restrict__ ch, int N)
{
  int n = blockIdx.x * blockDim.x + threadIdx.x;
  if (n >= N) return;
  float dt = fmaxf(ct[n], 1.0f);
  float dh = fmaxf(ch[n], 1.0f);
  f[n*2+0] /= dt; f[n*2+1] /= dt;
  g[n*2+0] /= dh; g[n*2+1] /= dh;
}

// ---------------------------------------------------------------------------
// Entity feature matrix h_e : [N][288] bf16 (266 real cols + zero pad)
// ---------------------------------------------------------------------------
__global__ void build_he(const float* __restrict__ emb, const float* __restrict__ nte,
                         const float* __restrict__ topic,
                         const float* __restrict__ f1, const float* __restrict__ f2,
                         const float* __restrict__ g1, const float* __restrict__ g2,
                         __hip_bfloat16* __restrict__ He, int N, int nText)
{
  int idx = blockIdx.x * blockDim.x + threadIdx.x;
  if (idx >= N * 288) return;
  int n = idx / 288, j = idx - n * 288;
  float v;
  if (j < 256)      v = (n < nText) ? emb[(size_t)n*256 + j] : nte[j];
  else if (j < 258) v = topic[n*2 + (j-256)];
  else if (j < 260) v = f1[n*2 + (j-258)];
  else if (j < 262) v = f2[n*2 + (j-260)];
  else if (j < 264) v = g1[n*2 + (j-262)];
  else if (j < 266) v = g2[n*2 + (j-264)];
  else              v = 0.0f;
  He[idx] = __float2bfloat16(v);
}

// ---------------------------------------------------------------------------
// Bayesian weight sampling (JAX threefry, partitionable semantics) — verified
// ---------------------------------------------------------------------------
__global__ void sample_kernel(int s,
                              const float* __restrict__ w1_mu, const float* __restrict__ w1_rho,
                              const float* __restrict__ b1_mu, const float* __restrict__ b1_rho,
                              const float* __restrict__ w2_mu, const float* __restrict__ w2_rho,
                              const float* __restrict__ b2_mu, const float* __restrict__ b2_rho,
                              float* __restrict__ W1s, float* __restrict__ b1s,
                              float* __restrict__ w2s, float* __restrict__ b2s)
{
  const int W1N = 267264;   // 256*1044
  int tid = blockIdx.x * blockDim.x + threadIdx.x;
  unsigned F0, F1;
  tf2x32(0u, 42u, 0u, (unsigned)s, F0, F1);   // fold_in(key(42), s)

  if (tid < W1N) {
    unsigned k0, k1; tf2x32(F0, F1, 0u, 0u, k0, k1);              // sk0
    unsigned o0, o1; tf2x32(k0, k1, 0u, (unsigned)tid, o0, o1);
    W1s[tid] = fmaf(rng_normal(o0 ^ o1), softplusf(w1_rho[tid]), w1_mu[tid]);
  } else if (tid < W1N + 256) {
    int m = tid - W1N;
    unsigned k0, k1; tf2x32(F0, F1, 0u, 1u, k0, k1);              // sk1
    unsigned o0, o1; tf2x32(k0, k1, 0u, (unsigned)m, o0, o1);
    b1s[m] = fmaf(rng_normal(o0 ^ o1), softplusf(b1_rho[m]), b1_mu[m]);
  } else if (tid < W1N + 512) {
    int m = tid - (W1N + 256);
    unsigned k0, k1; tf2x32(F0, F1, 0u, 2u, k0, k1);              // sk2
    unsigned o0, o1; tf2x32(k0, k1, 0u, (unsigned)m, o0, o1);
    w2s[m] = fmaf(rng_normal(o0 ^ o1), softplusf(w2_rho[m]), w2_mu[m]);
  } else if (tid == W1N + 512) {
    unsigned k0, k1; tf2x32(F0, F1, 0u, 3u, k0, k1);              // sk3
    unsigned o0, o1; tf2x32(k0, k1, 0u, 0u, o0, o1);
    b2s[0] = fmaf(rng_normal(o0 ^ o1), softplusf(b2_rho[0]), b2_mu[0]);
  }
}

// Pack A = [W1[:,256:522]; W1[:,778:1044]] -> As[512][288] bf16 (zero-padded K)
__global__ void pack_kernel(const float* __restrict__ W1s, __hip_bfloat16* __restrict__ As)
{
  int idx = blockIdx.x * blockDim.x + threadIdx.x;
  if (idx >= 512 * 288) return;
  int m = idx / 288, j = idx - m * 288;
  float v = 0.0f;
  if (j < 266) v = (m < 256) ? W1s[m*1044 + 256 + j] : W1s[(m-256)*1044 + 778 + j];
  As[idx] = __float2bfloat16(v);
}

// c[k] = b1s[k] + sum_j W1s[k][j] * q[j]  — one wave per k, coalesced
__global__ void c_kernel(const float* __restrict__ W1s, const float* __restrict__ b1s,
                         const float* __restrict__ q, float* __restrict__ cvec)
{
  int k = blockIdx.x * 4 + (threadIdx.x >> 6);
  int lane = threadIdx.x & 63;
  float4 v  = *reinterpret_cast<const float4*>(&W1s[(size_t)k * 1044 + lane * 4]);
  float4 qv = *reinterpret_cast<const float4*>(&q[lane * 4]);
  float acc = v.x*qv.x + v.y*qv.y + v.z*qv.z + v.w*qv.w;
  #pragma unroll
  for (int off = 32; off >= 1; off >>= 1) acc += __shfl_down(acc, off, 64);
  if (lane == 0) cvec[k] = acc + b1s[k];
}

// Ar[r][k] = sum_j W1s[k][522+j] * rel[r][j]
__global__ void ar_kernel(const float* __restrict__ W1s, const float* __restrict__ rel,
                          float* __restrict__ Ar)
{
  __shared__ float rsh[256];
  int r = blockIdx.x, k = threadIdx.x;
  rsh[k] = rel[(size_t)r*256 + k];
  __syncthreads();
  float acc = 0.0f;
  for (int j = 0; j < 256; ++j) acc = fmaf(W1s[k*1044 + 522 + j], rsh[j], acc);
  Ar[(size_t)r*256 + k] = acc;
}

// ---------------------------------------------------------------------------
// MFMA GEMM v2: U[n][m] = sum_k He[n][k] * As[m][k]; bf16 in/out, f32 acc.
// Block = 4 waves x 32 entity rows = 128 rows, ALL 512 m inside (m-loop).
// A fragments (full K=288) live in registers: He is read ONCE per sample.
// B (As, 288 KB) is L2-resident. No LDS, no barriers.
// ---------------------------------------------------------------------------
__global__ __launch_bounds__(256, 2) void gemm_mfma(const __hip_bfloat16* __restrict__ He,
                                                    const __hip_bfloat16* __restrict__ As,
                                                    __hip_bfloat16* __restrict__ U, int nEnt)
{
  const int wid  = threadIdx.x >> 6;
  const int lane = threadIdx.x & 63;
  const int n0 = blockIdx.x * 128 + wid * 32;
  const int lr = lane & 15;
  const int lk = (lane >> 4) * 8;

  int na = n0 + lr, nb = n0 + 16 + lr;
  const short* pa = (const short*)He + (size_t)(na < nEnt ? na : 0) * 288 + lk;
  const short* pb = (const short*)He + (size_t)(nb < nEnt ? nb : 0) * 288 + lk;

  short8 a[9][2];
  #pragma unroll
  for (int ks = 0; ks < 9; ++ks) {
    a[ks][0] = *reinterpret_cast<const short8*>(pa + ks * 32);
    a[ks][1] = *reinterpret_cast<const short8*>(pb + ks * 32);
  }

  const int rowbase = (lane >> 4) * 4;
  #pragma unroll 1
  for (int mt = 0; mt < 4; ++mt) {
    const int m0 = mt * 128;
    const short* pB = (const short*)As + (size_t)(m0 + lr) * 288 + lk;
    f32x4 acc[2][8] = {};
    #pragma unroll
    for (int ks = 0; ks < 9; ++ks) {
      short8 b[8];
      #pragma unroll
      for (int j = 0; j < 8; ++j)
        b[j] = *reinterpret_cast<const short8*>(pB + (size_t)j * 16 * 288 + ks * 32);
      #pragma unroll
      for (int j = 0; j < 8; ++j) {
        acc[0][j] = __builtin_amdgcn_mfma_f32_16x16x32_bf16(a[ks][0], b[j], acc[0][j], 0, 0, 0);
        acc[1][j] = __builtin_amdgcn_mfma_f32_16x16x32_bf16(a[ks][1], b[j], acc[1][j], 0, 0, 0);
      }
    }
    // D layout: col(m) = lane&15, row(n) = (lane>>4)*4 + r   [m89-verified]
    #pragma unroll
    for (int nf = 0; nf < 2; ++nf) {
      #pragma unroll
      for (int r = 0; r < 4; ++r) {
        int n = n0 + nf * 16 + rowbase + r;
        if (n < nEnt) {
          #pragma unroll
          for (int j = 0; j < 8; ++j)
            U[(size_t)n * 512 + m0 + j * 16 + lr] = __float2bfloat16(acc[nf][j][r]);
        }
      }
    }
  }
}

// ---------------------------------------------------------------------------
// Edge pass: 32 lanes per edge, 8 m-values per lane (bf16 U rows).
// pre[k] = c[k] + U[h][k] + Ar[r][k] + U[t][256+k];  out += w2 . relu(pre) + b2
// mode 0: store, 1: accumulate, 2: accumulate + *0.2
// ---------------------------------------------------------------------------
__global__ __launch_bounds__(256) void edge_kernel(const int* __restrict__ h,
                                                   const int* __restrict__ t,
                                                   const int* __restrict__ r,
                                                   const __hip_bfloat16* __restrict__ U,
                                                   const float* __restrict__ Ar,
                                                   const float* __restrict__ cvec,
                                                   const float* __restrict__ w2s,
                                                   const float* __restrict__ b2s,
                                                   float* __restrict__ out, int E, int mode)
{
  int e = blockIdx.x * 8 + (threadIdx.x >> 5);
  int l = threadIdx.x & 31;
  if (e >= E) return;
  int hh = h[e], tt = t[e], rr = r[e];
  const ushort* Ub = (const ushort*)U;

  uint4 uhv = *reinterpret_cast<const uint4*>(Ub + (size_t)hh * 512 + l * 8);
  uint4 utv = *reinterpret_cast<const uint4*>(Ub + (size_t)tt * 512 + 256 + l * 8);
  float4 ar0 = *reinterpret_cast<const float4*>(&Ar[(size_t)rr * 256 + l * 8]);
  float4 ar1 = *reinterpret_cast<const float4*>(&Ar[(size_t)rr * 256 + l * 8 + 4]);
  float4 c0  = *reinterpret_cast<const float4*>(&cvec[l * 8]);
  float4 c1  = *reinterpret_cast<const float4*>(&cvec[l * 8 + 4]);
  float4 w0  = *reinterpret_cast<const float4*>(&w2s[l * 8]);
  float4 w1  = *reinterpret_cast<const float4*>(&w2s[l * 8 + 4]);

  float uh[8], ut[8];
  uh[0] = __uint_as_float(uhv.x << 16); uh[1] = __uint_as_float(uhv.x & 0xFFFF0000u);
  uh[2] = __uint_as_float(uhv.y << 16); uh[3] = __uint_as_float(uhv.y & 0xFFFF0000u);
  uh[4] = __uint_as_float(uhv.z << 16); uh[5] = __uint_as_float(uhv.z & 0xFFFF0000u);
  uh[6] = __uint_as_float(uhv.w << 16); uh[7] = __uint_as_float(uhv.w & 0xFFFF0000u);
  ut[0] = __uint_as_float(utv.x << 16); ut[1] = __uint_as_float(utv.x & 0xFFFF0000u);
  ut[2] = __uint_as_float(utv.y << 16); ut[3] = __uint_as_float(utv.y & 0xFFFF0000u);
  ut[4] = __uint_as_float(utv.z << 16); ut[5] = __uint_as_float(utv.z & 0xFFFF0000u);
  ut[6] = __uint_as_float(utv.w << 16); ut[7] = __uint_as_float(utv.w & 0xFFFF0000u);

  const float cc[8] = {c0.x, c0.y, c0.z, c0.w, c1.x, c1.y, c1.z, c1.w};
  const float aa[8] = {ar0.x, ar0.y, ar0.z, ar0.w, ar1.x, ar1.y, ar1.z, ar1.w};
  const float ww[8] = {w0.x, w0.y, w0.z, w0.w, w1.x, w1.y, w1.z, w1.w};

  float sum = 0.0f;
  #pragma unroll
  for (int i = 0; i < 8; ++i)
    sum += ww[i] * fmaxf(cc[i] + uh[i] + aa[i] + ut[i], 0.0f);

  #pragma unroll
  for (int off = 16; off >= 1; off >>= 1) sum += __shfl_down(sum, off, 32);

  if (l == 0) {
    float v = sum + b2s[0];
    if (mode == 0)      out[e] = v;
    else if (mode == 1) out[e] += v;
    else                out[e] = (out[e] + v) * 0.2f;
  }
}

// ---------------------------------------------------------------------------
// Host launcher
// ---------------------------------------------------------------------------
extern "C" void kernel_launch(void* const* d_in, const int* in_sizes, int n_in,
                              void* d_out, int out_size, void* d_ws, size_t ws_size,
                              hipStream_t stream)
{
  const int*   h_id  = (const int*)  d_in[0];
  const int*   r_id  = (const int*)  d_in[1];
  const int*   t_id  = (const int*)  d_in[2];
  const float* q     = (const float*)d_in[3];
  const float* emb   = (const float*)d_in[4];
  const float* rel   = (const float*)d_in[6];
  const float* topic = (const float*)d_in[7];
  const float* nte   = (const float*)d_in[8];
  const float* w1_mu = (const float*)d_in[9];
  const float* w1_rho= (const float*)d_in[10];
  const float* b1_mu = (const float*)d_in[11];
  const float* b1_rho= (const float*)d_in[12];
  const float* w2_mu = (const float*)d_in[13];
  const float* w2_rho= (const float*)d_in[14];
  const float* b2_mu = (const float*)d_in[15];
  const float* b2_rho= (const float*)d_in[16];

  const int E     = in_sizes[0];
  const int nText = in_sizes[4] / 256;
  const int N     = in_sizes[7] / 2;
  const int NR    = in_sizes[6] / 256;
  float* out = (float*)d_out;

  char* ws = (char*)d_ws;
  size_t off = 0;
  auto alloc = [&](size_t bytes) -> void* {
    void* p = (void*)(ws + off);
    off += (bytes + 255) & ~(size_t)255;
    return p;
  };
  __hip_bfloat16* He  = (__hip_bfloat16*)alloc((size_t)N * 288 * 2);
  __hip_bfloat16* U   = (__hip_bfloat16*)alloc((size_t)N * 512 * 2);
  __hip_bfloat16* As  = (__hip_bfloat16*)alloc(512 * 288 * 2);
  float* W1s  = (float*)alloc(267264 * 4);
  float* b1s  = (float*)alloc(256 * 4);
  float* w2s  = (float*)alloc(256 * 4);
  float* b2s  = (float*)alloc(64 * 4);
  float* cvec = (float*)alloc(256 * 4);
  float* Ar   = (float*)alloc((size_t)NR * 256 * 4);
  float* cnt_t = (float*)alloc((size_t)N * 4);
  float* cnt_h = (float*)alloc((size_t)N * 4);
  float* f1 = (float*)alloc((size_t)2 * N * 4);
  float* f2 = (float*)alloc((size_t)2 * N * 4);
  float* g1 = (float*)alloc((size_t)2 * N * 4);
  float* g2 = (float*)alloc((size_t)2 * N * 4);

  // zero the atomic-accumulated DDE region (cnt_t .. g2, contiguous)
  size_t dde_bytes = (size_t)((char*)(g2 + 2*(size_t)N) - (char*)cnt_t);
  hipMemsetAsync(cnt_t, 0, dde_bytes, stream);

  int eb = (E + 255) / 256;
  int nb = (N + 255) / 256;
  dde_count   <<<eb, 256, 0, stream>>>(h_id, t_id, cnt_t, cnt_h, E);
  dde_scatter1<<<eb, 256, 0, stream>>>(h_id, t_id, topic, f1, g1, E);
  dde_norm    <<<nb, 256, 0, stream>>>(f1, g1, cnt_t, cnt_h, N);
  dde_scatter2<<<eb, 256, 0, stream>>>(h_id, t_id, f1, g1, f2, g2, E);
  dde_norm    <<<nb, 256, 0, stream>>>(f2, g2, cnt_t, cnt_h, N);

  int heb = ((int)((size_t)N * 288) + 255) / 256;
  build_he<<<heb, 256, 0, stream>>>(emb, nte, topic, f1, f2, g1, g2, He, N, nText);

  int ggrid = (N + 127) / 128;
  for (int s = 0; s < 5; ++s) {
    sample_kernel<<<(267264 + 513 + 255) / 256, 256, 0, stream>>>(
        s, w1_mu, w1_rho, b1_mu, b1_rho, w2_mu, w2_rho, b2_mu, b2_rho,
        W1s, b1s, w2s, b2s);
    pack_kernel<<<(512*288 + 255)/256, 256, 0, stream>>>(W1s, As);
    c_kernel   <<<64, 256, 0, stream>>>(W1s, b1s, q, cvec);
    ar_kernel  <<<NR, 256, 0, stream>>>(W1s, rel, Ar);
    gemm_mfma  <<<ggrid, 256, 0, stream>>>(He, As, U, N);
    int mode = (s == 0) ? 0 : ((s == 4) ? 2 : 1);
    edge_kernel<<<(E + 7) / 8, 256, 0, stream>>>(h_id, t_id, r_id, U, Ar, cvec,
                                                 w2s, b2s, out, E, mode);
  }
  (void)n_in; (void)out_size; (void)ws_size;
}

// Round 5
// 1315.108 us; speedup vs baseline: 1.3389x; 1.3389x over previous
//
#include <hip/hip_runtime.h>
#include <hip/hip_bf16.h>

typedef __attribute__((ext_vector_type(8))) short short8;
typedef __attribute__((ext_vector_type(4))) float f32x4;

#define GLOAD16(g, l) __builtin_amdgcn_global_load_lds( \
    (const __attribute__((address_space(1))) void*)(g), \
    (__attribute__((address_space(3))) void*)(l), 16, 0, 0)

// ---------------------------------------------------------------------------
// Threefry2x32 (JAX partitionable semantics) + erfinv (XLA f32 polynomial)
// ---------------------------------------------------------------------------
#define TF_ROUND(r) { x0 += x1; x1 = ((x1<<(r))|(x1>>(32-(r)))); x1 ^= x0; }

__device__ __forceinline__ void tf2x32(unsigned k0, unsigned k1, unsigned x0, unsigned x1,
                                       unsigned &o0, unsigned &o1)
{
  unsigned ks2 = k0 ^ k1 ^ 0x1BD11BDAu;
  x0 += k0; x1 += k1;
  TF_ROUND(13) TF_ROUND(15) TF_ROUND(26) TF_ROUND(6)
  x0 += k1;  x1 += ks2 + 1u;
  TF_ROUND(17) TF_ROUND(29) TF_ROUND(16) TF_ROUND(24)
  x0 += ks2; x1 += k0 + 2u;
  TF_ROUND(13) TF_ROUND(15) TF_ROUND(26) TF_ROUND(6)
  x0 += k0;  x1 += k1 + 3u;
  TF_ROUND(17) TF_ROUND(29) TF_ROUND(16) TF_ROUND(24)
  x0 += k1;  x1 += ks2 + 4u;
  TF_ROUND(13) TF_ROUND(15) TF_ROUND(26) TF_ROUND(6)
  x0 += ks2; x1 += k0 + 5u;
  o0 = x0; o1 = x1;
}

__device__ __forceinline__ float erfinv_f(float x)
{
  float w = -log1pf(-x * x);
  float p;
  if (w < 5.0f) {
    w -= 2.5f;
    p = 2.81022636e-08f;
    p = fmaf(p, w, 3.43273939e-07f);
    p = fmaf(p, w, -3.5233877e-06f);
    p = fmaf(p, w, -4.39150654e-06f);
    p = fmaf(p, w, 0.00021858087f);
    p = fmaf(p, w, -0.00125372503f);
    p = fmaf(p, w, -0.00417768164f);
    p = fmaf(p, w, 0.246640727f);
    p = fmaf(p, w, 1.50140941f);
  } else {
    w = sqrtf(w) - 3.0f;
    p = -0.000200214257f;
    p = fmaf(p, w, 0.000100950558f);
    p = fmaf(p, w, 0.00134934322f);
    p = fmaf(p, w, -0.00367342844f);
    p = fmaf(p, w, 0.00573950773f);
    p = fmaf(p, w, -0.0076224613f);
    p = fmaf(p, w, 0.00943887047f);
    p = fmaf(p, w, 1.00167406f);
    p = fmaf(p, w, 2.83297682f);
  }
  return p * x;
}

__device__ __forceinline__ float rng_normal(unsigned b)
{
  float f = __uint_as_float((b >> 9) | 0x3f800000u) - 1.0f;  // [0,1)
  const float lo = -0.99999994f;
  float u = fmaxf(lo, f * 2.0f + lo);
  return 1.41421356f * erfinv_f(u);
}

__device__ __forceinline__ float softplusf(float x) { return log1pf(expf(x)); }

// ---------------------------------------------------------------------------
// DDE (PEConv mean) kernels
// ---------------------------------------------------------------------------
__global__ void dde_count(const int* __restrict__ h, const int* __restrict__ t,
                          float* __restrict__ cnt_t, float* __restrict__ cnt_h, int E)
{
  int e = blockIdx.x * blockDim.x + threadIdx.x;
  if (e >= E) return;
  atomicAdd(&cnt_t[t[e]], 1.0f);
  atomicAdd(&cnt_h[h[e]], 1.0f);
}

__global__ void dde_scatter1(const int* __restrict__ h, const int* __restrict__ t,
                             const float* __restrict__ topic,
                             float* __restrict__ f1, float* __restrict__ g1, int E)
{
  int e = blockIdx.x * blockDim.x + threadIdx.x;
  if (e >= E) return;
  int hh = h[e], tt = t[e];
  atomicAdd(&f1[tt*2+0], topic[hh*2+0]);
  atomicAdd(&f1[tt*2+1], topic[hh*2+1]);
  atomicAdd(&g1[hh*2+0], topic[tt*2+0]);
  atomicAdd(&g1[hh*2+1], topic[tt*2+1]);
}

__global__ void dde_scatter2(const int* __restrict__ h, const int* __restrict__ t,
                             const float* __restrict__ f1, const float* __restrict__ g1,
                             float* __restrict__ f2, float* __restrict__ g2, int E)
{
  int e = blockIdx.x * blockDim.x + threadIdx.x;
  if (e >= E) return;
  int hh = h[e], tt = t[e];
  atomicAdd(&f2[tt*2+0], f1[hh*2+0]);
  atomicAdd(&f2[tt*2+1], f1[hh*2+1]);
  atomicAdd(&g2[hh*2+0], g1[tt*2+0]);
  atomicAdd(&g2[hh*2+1], g1[tt*2+1]);
}

__global__ void dde_norm(float* __restrict__ f, float* __restrict__ g,
                         const float* __restrict__ ct, const float* __restrict__ ch, int N)
{
  int n = blockIdx.x * blockDim.x + threadIdx.x;
  if (n >= N) return;
  float dt = fmaxf(ct[n], 1.0f);
  float dh = fmaxf(ch[n], 1.0f);
  f[n*2+0] /= dt; f[n*2+1] /= dt;
  g[n*2+0] /= dh; g[n*2+1] /= dh;
}

// ---------------------------------------------------------------------------
// Entity feature matrix h_e : [N][288] bf16 (266 real cols + zero pad)
// ---------------------------------------------------------------------------
__global__ void build_he(const float* __restrict__ emb, const float* __restrict__ nte,
                         const float* __restrict__ topic,
                         const float* __restrict__ f1, const float* __restrict__ f2,
                         const float* __restrict__ g1, const float* __restrict__ g2,
                         __hip_bfloat16* __restrict__ He, int N, int nText)
{
  int idx = blockIdx.x * blockDim.x + threadIdx.x;
  if (idx >= N * 288) return;
  int n = idx / 288, j = idx - n * 288;
  float v;
  if (j < 256)      v = (n < nText) ? emb[(size_t)n*256 + j] : nte[j];
  else if (j < 258) v = topic[n*2 + (j-256)];
  else if (j < 260) v = f1[n*2 + (j-258)];
  else if (j < 262) v = f2[n*2 + (j-260)];
  else if (j < 264) v = g1[n*2 + (j-262)];
  else if (j < 266) v = g2[n*2 + (j-264)];
  else              v = 0.0f;
  He[idx] = __float2bfloat16(v);
}

// ---------------------------------------------------------------------------
// Bayesian weight sampling (JAX threefry, partitionable semantics) — verified
// ---------------------------------------------------------------------------
__global__ void sample_kernel(int s,
                              const float* __restrict__ w1_mu, const float* __restrict__ w1_rho,
                              const float* __restrict__ b1_mu, const float* __restrict__ b1_rho,
                              const float* __restrict__ w2_mu, const float* __restrict__ w2_rho,
                              const float* __restrict__ b2_mu, const float* __restrict__ b2_rho,
                              float* __restrict__ W1s, float* __restrict__ b1s,
                              float* __restrict__ w2s, float* __restrict__ b2s)
{
  const int W1N = 267264;   // 256*1044
  int tid = blockIdx.x * blockDim.x + threadIdx.x;
  unsigned F0, F1;
  tf2x32(0u, 42u, 0u, (unsigned)s, F0, F1);   // fold_in(key(42), s)

  if (tid < W1N) {
    unsigned k0, k1; tf2x32(F0, F1, 0u, 0u, k0, k1);              // sk0
    unsigned o0, o1; tf2x32(k0, k1, 0u, (unsigned)tid, o0, o1);
    W1s[tid] = fmaf(rng_normal(o0 ^ o1), softplusf(w1_rho[tid]), w1_mu[tid]);
  } else if (tid < W1N + 256) {
    int m = tid - W1N;
    unsigned k0, k1; tf2x32(F0, F1, 0u, 1u, k0, k1);              // sk1
    unsigned o0, o1; tf2x32(k0, k1, 0u, (unsigned)m, o0, o1);
    b1s[m] = fmaf(rng_normal(o0 ^ o1), softplusf(b1_rho[m]), b1_mu[m]);
  } else if (tid < W1N + 512) {
    int m = tid - (W1N + 256);
    unsigned k0, k1; tf2x32(F0, F1, 0u, 2u, k0, k1);              // sk2
    unsigned o0, o1; tf2x32(k0, k1, 0u, (unsigned)m, o0, o1);
    w2s[m] = fmaf(rng_normal(o0 ^ o1), softplusf(w2_rho[m]), w2_mu[m]);
  } else if (tid == W1N + 512) {
    unsigned k0, k1; tf2x32(F0, F1, 0u, 3u, k0, k1);              // sk3
    unsigned o0, o1; tf2x32(k0, k1, 0u, 0u, o0, o1);
    b2s[0] = fmaf(rng_normal(o0 ^ o1), softplusf(b2_rho[0]), b2_mu[0]);
  }
}

// Pack A = [W1[:,256:522]; W1[:,778:1044]] -> As[512][288] bf16 (zero-padded K)
__global__ void pack_kernel(const float* __restrict__ W1s, __hip_bfloat16* __restrict__ As)
{
  int idx = blockIdx.x * blockDim.x + threadIdx.x;
  if (idx >= 512 * 288) return;
  int m = idx / 288, j = idx - m * 288;
  float v = 0.0f;
  if (j < 266) v = (m < 256) ? W1s[m*1044 + 256 + j] : W1s[(m-256)*1044 + 778 + j];
  As[idx] = __float2bfloat16(v);
}

// c[k] = b1s[k] + sum_j W1s[k][j] * q[j]  — one wave per k, coalesced
__global__ void c_kernel(const float* __restrict__ W1s, const float* __restrict__ b1s,
                         const float* __restrict__ q, float* __restrict__ cvec)
{
  int k = blockIdx.x * 4 + (threadIdx.x >> 6);
  int lane = threadIdx.x & 63;
  float4 v  = *reinterpret_cast<const float4*>(&W1s[(size_t)k * 1044 + lane * 4]);
  float4 qv = *reinterpret_cast<const float4*>(&q[lane * 4]);
  float acc = v.x*qv.x + v.y*qv.y + v.z*qv.z + v.w*qv.w;
  #pragma unroll
  for (int off = 32; off >= 1; off >>= 1) acc += __shfl_down(acc, off, 64);
  if (lane == 0) cvec[k] = acc + b1s[k];
}

// Ar[r][k] = sum_j W1s[k][522+j] * rel[r][j]
__global__ void ar_kernel(const float* __restrict__ W1s, const float* __restrict__ rel,
                          float* __restrict__ Ar)
{
  __shared__ float rsh[256];
  int r = blockIdx.x, k = threadIdx.x;
  rsh[k] = rel[(size_t)r*256 + k];
  __syncthreads();
  float acc = 0.0f;
  for (int j = 0; j < 256; ++j) acc = fmaf(W1s[k*1044 + 522 + j], rsh[j], acc);
  Ar[(size_t)r*256 + k] = acc;
}

// ---------------------------------------------------------------------------
// MFMA GEMM v3: U[n][m] = sum_k He[n][k] * As[m][k]; bf16 in/out, f32 acc.
// 128n x 128m tile, BK=32 (9 steps), 4 waves each 64x64 (acc 4x4 of 16x16).
// Double-buffered LDS staged via global_load_lds width-16 (T3 2-phase recipe).
// XOR-swizzle (4-way max): LDS granule (row,gc) holds global k-granule
// gc^(row&3); applied on the SOURCE address (gload_lds writes linear) and on
// the ds_read address.  grid = (4 m-tiles, nb n-tiles), x fastest -> He read
// once per dispatch via L2/L3 sharing across the 4 m-tiles.
// ---------------------------------------------------------------------------
__global__ __launch_bounds__(256) void gemm_mfma(const __hip_bfloat16* __restrict__ Heb,
                                                 const __hip_bfloat16* __restrict__ Asb,
                                                 __hip_bfloat16* __restrict__ U, int nEnt)
{
  __shared__ short lA[2][4096];   // [row 0..127][k 0..31] swizzled, 8 KB each
  __shared__ short lB[2][4096];

  const int tid  = threadIdx.x;
  const int lane = tid & 63;
  const int wid  = tid >> 6;
  const int wr   = wid >> 1;          // n half (0/1)
  const int wc   = wid & 1;           // m half (0/1)
  const int m0   = blockIdx.x * 128;
  const int n0   = blockIdx.y * 128;
  const short* He = (const short*)Heb;
  const short* As = (const short*)Asb;

  const int lr  = lane & 15;
  const int kb  = (lane >> 4) * 16;        // k-granule byte offset (0..48)
  const int swz = (lane & 3) << 4;         // row&3 == lane&3 for 16-aligned rowbase

  // staging: thread covers granules tid and tid+256 of each 8KB tile
  const int g0row = tid >> 2,  g0c = tid & 3;
  const int g1row = (tid + 256) >> 2, g1c = tid & 3;  // (tid+256)&3 == tid&3
  const int maxA = nEnt - n0 - 1;          // clamp row for last block
  const int a0r = g0row <= maxA ? g0row : maxA;
  const int a1r = g1row <= maxA ? g1row : maxA;
  const size_t aoff0 = (size_t)a0r * 288 + (g0c ^ (g0row & 3)) * 8;
  const size_t aoff1 = (size_t)a1r * 288 + (g1c ^ (g1row & 3)) * 8;
  const size_t boff0 = (size_t)g0row * 288 + (g0c ^ (g0row & 3)) * 8;
  const size_t boff1 = (size_t)g1row * 288 + (g1c ^ (g1row & 3)) * 8;
  const short* gA = He + (size_t)n0 * 288;
  const short* gB = As + (size_t)m0 * 288;

  #define STAGE(buf, k0)                                              \
    { GLOAD16(gA + (k0) + aoff0, (char*)lA[buf] + tid * 16);          \
      GLOAD16(gA + (k0) + aoff1, (char*)lA[buf] + tid * 16 + 4096);   \
      GLOAD16(gB + (k0) + boff0, (char*)lB[buf] + tid * 16);          \
      GLOAD16(gB + (k0) + boff1, (char*)lB[buf] + tid * 16 + 4096); }

  f32x4 acc[4][4] = {};

  STAGE(0, 0)
  __syncthreads();   // compiler emits vmcnt(0) drain before barrier

  #pragma unroll 1
  for (int ks = 0; ks < 9; ++ks) {
    const int cur = ks & 1;
    if (ks < 8) STAGE(cur ^ 1, (ks + 1) * 32)

    short8 a[4], b[4];
    #pragma unroll
    for (int i = 0; i < 4; ++i) {
      int rowA = wr * 64 + i * 16 + lr;
      a[i] = *reinterpret_cast<const short8*>((const char*)lA[cur] + rowA * 64 + (kb ^ swz));
      int rowB = wc * 64 + i * 16 + lr;
      b[i] = *reinterpret_cast<const short8*>((const char*)lB[cur] + rowB * 64 + (kb ^ swz));
    }
    #pragma unroll
    for (int i = 0; i < 4; ++i)
      #pragma unroll
      for (int j = 0; j < 4; ++j)
        acc[i][j] = __builtin_amdgcn_mfma_f32_16x16x32_bf16(a[i], b[j], acc[i][j], 0, 0, 0);

    __syncthreads();  // drains vmcnt(0)+lgkmcnt(0): next buffer staged & safe
  }
  #undef STAGE

  // C/D layout: col = lane&15, row = (lane>>4)*4 + r  [m89-verified]
  const int rg = (lane >> 4) * 4;
  #pragma unroll
  for (int i = 0; i < 4; ++i) {
    #pragma unroll
    for (int r = 0; r < 4; ++r) {
      int n = n0 + wr * 64 + i * 16 + rg + r;
      if (n < nEnt) {
        #pragma unroll
        for (int j = 0; j < 4; ++j)
          U[(size_t)n * 512 + m0 + wc * 64 + j * 16 + lr] = __float2bfloat16(acc[i][j][r]);
      }
    }
  }
}

// ---------------------------------------------------------------------------
// Edge pass: 32 lanes per edge, 8 m-values per lane (bf16 U rows).
// pre[k] = c[k] + U[h][k] + Ar[r][k] + U[t][256+k];  out += w2 . relu(pre) + b2
// mode 0: store, 1: accumulate, 2: accumulate + *0.2
// ---------------------------------------------------------------------------
__global__ __launch_bounds__(256) void edge_kernel(const int* __restrict__ h,
                                                   const int* __restrict__ t,
                                                   const int* __restrict__ r,
                                                   const __hip_bfloat16* __restrict__ U,
                                                   const float* __restrict__ Ar,
                                                   const float* __restrict__ cvec,
                                                   const float* __restrict__ w2s,
                                                   const float* __restrict__ b2s,
                                                   float* __restrict__ out, int E, int mode)
{
  int e = blockIdx.x * 8 + (threadIdx.x >> 5);
  int l = threadIdx.x & 31;
  if (e >= E) return;
  int hh = h[e], tt = t[e], rr = r[e];
  const ushort* Ub = (const ushort*)U;

  uint4 uhv = *reinterpret_cast<const uint4*>(Ub + (size_t)hh * 512 + l * 8);
  uint4 utv = *reinterpret_cast<const uint4*>(Ub + (size_t)tt * 512 + 256 + l * 8);
  float4 ar0 = *reinterpret_cast<const float4*>(&Ar[(size_t)rr * 256 + l * 8]);
  float4 ar1 = *reinterpret_cast<const float4*>(&Ar[(size_t)rr * 256 + l * 8 + 4]);
  float4 c0  = *reinterpret_cast<const float4*>(&cvec[l * 8]);
  float4 c1  = *reinterpret_cast<const float4*>(&cvec[l * 8 + 4]);
  float4 w0  = *reinterpret_cast<const float4*>(&w2s[l * 8]);
  float4 w1  = *reinterpret_cast<const float4*>(&w2s[l * 8 + 4]);

  float uh[8], ut[8];
  uh[0] = __uint_as_float(uhv.x << 16); uh[1] = __uint_as_float(uhv.x & 0xFFFF0000u);
  uh[2] = __uint_as_float(uhv.y << 16); uh[3] = __uint_as_float(uhv.y & 0xFFFF0000u);
  uh[4] = __uint_as_float(uhv.z << 16); uh[5] = __uint_as_float(uhv.z & 0xFFFF0000u);
  uh[6] = __uint_as_float(uhv.w << 16); uh[7] = __uint_as_float(uhv.w & 0xFFFF0000u);
  ut[0] = __uint_as_float(utv.x << 16); ut[1] = __uint_as_float(utv.x & 0xFFFF0000u);
  ut[2] = __uint_as_float(utv.y << 16); ut[3] = __uint_as_float(utv.y & 0xFFFF0000u);
  ut[4] = __uint_as_float(utv.z << 16); ut[5] = __uint_as_float(utv.z & 0xFFFF0000u);
  ut[6] = __uint_as_float(utv.w << 16); ut[7] = __uint_as_float(utv.w & 0xFFFF0000u);

  const float cc[8] = {c0.x, c0.y, c0.z, c0.w, c1.x, c1.y, c1.z, c1.w};
  const float aa[8] = {ar0.x, ar0.y, ar0.z, ar0.w, ar1.x, ar1.y, ar1.z, ar1.w};
  const float ww[8] = {w0.x, w0.y, w0.z, w0.w, w1.x, w1.y, w1.z, w1.w};

  float sum = 0.0f;
  #pragma unroll
  for (int i = 0; i < 8; ++i)
    sum += ww[i] * fmaxf(cc[i] + uh[i] + aa[i] + ut[i], 0.0f);

  #pragma unroll
  for (int off = 16; off >= 1; off >>= 1) sum += __shfl_down(sum, off, 32);

  if (l == 0) {
    float v = sum + b2s[0];
    if (mode == 0)      out[e] = v;
    else if (mode == 1) out[e] += v;
    else                out[e] = (out[e] + v) * 0.2f;
  }
}

// ---------------------------------------------------------------------------
// Host launcher
// ---------------------------------------------------------------------------
extern "C" void kernel_launch(void* const* d_in, const int* in_sizes, int n_in,
                              void* d_out, int out_size, void* d_ws, size_t ws_size,
                              hipStream_t stream)
{
  const int*   h_id  = (const int*)  d_in[0];
  const int*   r_id  = (const int*)  d_in[1];
  const int*   t_id  = (const int*)  d_in[2];
  const float* q     = (const float*)d_in[3];
  const float* emb   = (const float*)d_in[4];
  const float* rel   = (const float*)d_in[6];
  const float* topic = (const float*)d_in[7];
  const float* nte   = (const float*)d_in[8];
  const float* w1_mu = (const float*)d_in[9];
  const float* w1_rho= (const float*)d_in[10];
  const float* b1_mu = (const float*)d_in[11];
  const float* b1_rho= (const float*)d_in[12];
  const float* w2_mu = (const float*)d_in[13];
  const float* w2_rho= (const float*)d_in[14];
  const float* b2_mu = (const float*)d_in[15];
  const float* b2_rho= (const float*)d_in[16];

  const int E     = in_sizes[0];
  const int nText = in_sizes[4] / 256;
  const int N     = in_sizes[7] / 2;
  const int NR    = in_sizes[6] / 256;
  float* out = (float*)d_out;

  char* ws = (char*)d_ws;
  size_t off = 0;
  auto alloc = [&](size_t bytes) -> void* {
    void* p = (void*)(ws + off);
    off += (bytes + 255) & ~(size_t)255;
    return p;
  };
  __hip_bfloat16* He  = (__hip_bfloat16*)alloc((size_t)N * 288 * 2);
  __hip_bfloat16* U   = (__hip_bfloat16*)alloc((size_t)N * 512 * 2);
  __hip_bfloat16* As  = (__hip_bfloat16*)alloc(512 * 288 * 2);
  float* W1s  = (float*)alloc(267264 * 4);
  float* b1s  = (float*)alloc(256 * 4);
  float* w2s  = (float*)alloc(256 * 4);
  float* b2s  = (float*)alloc(64 * 4);
  float* cvec = (float*)alloc(256 * 4);
  float* Ar   = (float*)alloc((size_t)NR * 256 * 4);
  float* cnt_t = (float*)alloc((size_t)N * 4);
  float* cnt_h = (float*)alloc((size_t)N * 4);
  float* f1 = (float*)alloc((size_t)2 * N * 4);
  float* f2 = (float*)alloc((size_t)2 * N * 4);
  float* g1 = (float*)alloc((size_t)2 * N * 4);
  float* g2 = (float*)alloc((size_t)2 * N * 4);

  // zero the atomic-accumulated DDE region (cnt_t .. g2, contiguous)
  size_t dde_bytes = (size_t)((char*)(g2 + 2*(size_t)N) - (char*)cnt_t);
  hipMemsetAsync(cnt_t, 0, dde_bytes, stream);

  int eb = (E + 255) / 256;
  int nb = (N + 255) / 256;
  dde_count   <<<eb, 256, 0, stream>>>(h_id, t_id, cnt_t, cnt_h, E);
  dde_scatter1<<<eb, 256, 0, stream>>>(h_id, t_id, topic, f1, g1, E);
  dde_norm    <<<nb, 256, 0, stream>>>(f1, g1, cnt_t, cnt_h, N);
  dde_scatter2<<<eb, 256, 0, stream>>>(h_id, t_id, f1, g1, f2, g2, E);
  dde_norm    <<<nb, 256, 0, stream>>>(f2, g2, cnt_t, cnt_h, N);

  int heb = ((int)((size_t)N * 288) + 255) / 256;
  build_he<<<heb, 256, 0, stream>>>(emb, nte, topic, f1, f2, g1, g2, He, N, nText);

  dim3 ggrid(4, (N + 127) / 128);
  for (int s = 0; s < 5; ++s) {
    sample_kernel<<<(267264 + 513 + 255) / 256, 256, 0, stream>>>(
        s, w1_mu, w1_rho, b1_mu, b1_rho, w2_mu, w2_rho, b2_mu, b2_rho,
        W1s, b1s, w2s, b2s);
    pack_kernel<<<(512*288 + 255)/256, 256, 0, stream>>>(W1s, As);
    c_kernel   <<<64, 256, 0, stream>>>(W1s, b1s, q, cvec);
    ar_kernel  <<<NR, 256, 0, stream>>>(W1s, rel, Ar);
    gemm_mfma  <<<ggrid, 256, 0, stream>>>(He, As, U, N);
    int mode = (s == 0) ? 0 : ((s == 4) ? 2 : 1);
    edge_kernel<<<(E + 7) / 8, 256, 0, stream>>>(h_id, t_id, r_id, U, Ar, cvec,
                                                 w2s, b2s, out, E, mode);
  }
  (void)n_in; (void)out_size; (void)ws_size;
}

// Round 6
// 1173.474 us; speedup vs baseline: 1.5005x; 1.1207x over previous
//
#include <hip/hip_runtime.h>
#include <hip/hip_bf16.h>

typedef __attribute__((ext_vector_type(8))) short short8;
typedef __attribute__((ext_vector_type(4))) float f32x4;
typedef unsigned long long u64;

#define GLOAD16(g, l) __builtin_amdgcn_global_load_lds( \
    (const __attribute__((address_space(1))) void*)(g), \
    (__attribute__((address_space(3))) void*)(l), 16, 0, 0)

#define FIXS 1048576.0f          // 2^20 fixed-point scale
#define FIXI (1.0f / 1048576.0f)

// ---------------------------------------------------------------------------
// Threefry2x32 (JAX partitionable semantics) + erfinv (XLA f32 polynomial)
// ---------------------------------------------------------------------------
#define TF_ROUND(r) { x0 += x1; x1 = ((x1<<(r))|(x1>>(32-(r)))); x1 ^= x0; }

__device__ __forceinline__ void tf2x32(unsigned k0, unsigned k1, unsigned x0, unsigned x1,
                                       unsigned &o0, unsigned &o1)
{
  unsigned ks2 = k0 ^ k1 ^ 0x1BD11BDAu;
  x0 += k0; x1 += k1;
  TF_ROUND(13) TF_ROUND(15) TF_ROUND(26) TF_ROUND(6)
  x0 += k1;  x1 += ks2 + 1u;
  TF_ROUND(17) TF_ROUND(29) TF_ROUND(16) TF_ROUND(24)
  x0 += ks2; x1 += k0 + 2u;
  TF_ROUND(13) TF_ROUND(15) TF_ROUND(26) TF_ROUND(6)
  x0 += k0;  x1 += k1 + 3u;
  TF_ROUND(17) TF_ROUND(29) TF_ROUND(16) TF_ROUND(24)
  x0 += k1;  x1 += ks2 + 4u;
  TF_ROUND(13) TF_ROUND(15) TF_ROUND(26) TF_ROUND(6)
  x0 += ks2; x1 += k0 + 5u;
  o0 = x0; o1 = x1;
}

__device__ __forceinline__ float erfinv_f(float x)
{
  float w = -log1pf(-x * x);
  float p;
  if (w < 5.0f) {
    w -= 2.5f;
    p = 2.81022636e-08f;
    p = fmaf(p, w, 3.43273939e-07f);
    p = fmaf(p, w, -3.5233877e-06f);
    p = fmaf(p, w, -4.39150654e-06f);
    p = fmaf(p, w, 0.00021858087f);
    p = fmaf(p, w, -0.00125372503f);
    p = fmaf(p, w, -0.00417768164f);
    p = fmaf(p, w, 0.246640727f);
    p = fmaf(p, w, 1.50140941f);
  } else {
    w = sqrtf(w) - 3.0f;
    p = -0.000200214257f;
    p = fmaf(p, w, 0.000100950558f);
    p = fmaf(p, w, 0.00134934322f);
    p = fmaf(p, w, -0.00367342844f);
    p = fmaf(p, w, 0.00573950773f);
    p = fmaf(p, w, -0.0076224613f);
    p = fmaf(p, w, 0.00943887047f);
    p = fmaf(p, w, 1.00167406f);
    p = fmaf(p, w, 2.83297682f);
  }
  return p * x;
}

__device__ __forceinline__ float rng_normal(unsigned b)
{
  float f = __uint_as_float((b >> 9) | 0x3f800000u) - 1.0f;  // [0,1)
  const float lo = -0.99999994f;
  float u = fmaxf(lo, f * 2.0f + lo);
  return 1.41421356f * erfinv_f(u);
}

__device__ __forceinline__ float softplusf(float x) { return log1pf(expf(x)); }

// ---------------------------------------------------------------------------
// DDE (PEConv mean) — packed fixed-point atomics.
// pass1: f1[t] += topic[h], cnt_t[t]++  (packed u64: count<<32 | x_fix; u32 y)
//        g1[h] += topic[t], cnt_h[h]++
// pass2: f2[t] += f1n[h] ; g2[h] += g1n[t]   (packed u64: y_fix<<32 | x_fix)
// ---------------------------------------------------------------------------
__global__ void dde_pass1(const int* __restrict__ h, const int* __restrict__ t,
                          const float* __restrict__ topic,
                          u64* __restrict__ Axc_t, unsigned* __restrict__ Ay_t,
                          u64* __restrict__ Axc_h, unsigned* __restrict__ Ay_h, int E)
{
  int e = blockIdx.x * blockDim.x + threadIdx.x;
  if (e >= E) return;
  int hh = h[e], tt = t[e];
  float2 th = *reinterpret_cast<const float2*>(&topic[hh * 2]);
  float2 tv = *reinterpret_cast<const float2*>(&topic[tt * 2]);
  atomicAdd(&Axc_t[tt], (1ULL << 32) | (unsigned)(th.x * FIXS + 0.5f));
  atomicAdd(&Ay_t[tt], (unsigned)(th.y * FIXS + 0.5f));
  atomicAdd(&Axc_h[hh], (1ULL << 32) | (unsigned)(tv.x * FIXS + 0.5f));
  atomicAdd(&Ay_h[hh], (unsigned)(tv.y * FIXS + 0.5f));
}

__global__ void dde_norm1(const u64* __restrict__ Axc_t, const unsigned* __restrict__ Ay_t,
                          const u64* __restrict__ Axc_h, const unsigned* __restrict__ Ay_h,
                          float* __restrict__ f1n, float* __restrict__ g1n, int N)
{
  int n = blockIdx.x * blockDim.x + threadIdx.x;
  if (n >= N) return;
  u64 at = Axc_t[n];
  float st = FIXI / fmaxf((float)(unsigned)(at >> 32), 1.0f);
  f1n[n*2+0] = (float)(unsigned)(at & 0xFFFFFFFFu) * st;
  f1n[n*2+1] = (float)Ay_t[n] * st;
  u64 ah = Axc_h[n];
  float sh = FIXI / fmaxf((float)(unsigned)(ah >> 32), 1.0f);
  g1n[n*2+0] = (float)(unsigned)(ah & 0xFFFFFFFFu) * sh;
  g1n[n*2+1] = (float)Ay_h[n] * sh;
}

__global__ void dde_pass2(const int* __restrict__ h, const int* __restrict__ t,
                          const float* __restrict__ f1n, const float* __restrict__ g1n,
                          u64* __restrict__ F2_t, u64* __restrict__ G2_h, int E)
{
  int e = blockIdx.x * blockDim.x + threadIdx.x;
  if (e >= E) return;
  int hh = h[e], tt = t[e];
  float2 fv = *reinterpret_cast<const float2*>(&f1n[hh * 2]);
  float2 gv = *reinterpret_cast<const float2*>(&g1n[tt * 2]);
  atomicAdd(&F2_t[tt], ((u64)(unsigned)(fv.y * FIXS + 0.5f) << 32) | (unsigned)(fv.x * FIXS + 0.5f));
  atomicAdd(&G2_h[hh], ((u64)(unsigned)(gv.y * FIXS + 0.5f) << 32) | (unsigned)(gv.x * FIXS + 0.5f));
}

__global__ void dde_norm2(const u64* __restrict__ F2_t, const u64* __restrict__ G2_h,
                          const u64* __restrict__ Axc_t, const u64* __restrict__ Axc_h,
                          float* __restrict__ f2n, float* __restrict__ g2n, int N)
{
  int n = blockIdx.x * blockDim.x + threadIdx.x;
  if (n >= N) return;
  float st = FIXI / fmaxf((float)(unsigned)(Axc_t[n] >> 32), 1.0f);
  u64 f = F2_t[n];
  f2n[n*2+0] = (float)(unsigned)(f & 0xFFFFFFFFu) * st;
  f2n[n*2+1] = (float)(unsigned)(f >> 32) * st;
  float sh = FIXI / fmaxf((float)(unsigned)(Axc_h[n] >> 32), 1.0f);
  u64 g = G2_h[n];
  g2n[n*2+0] = (float)(unsigned)(g & 0xFFFFFFFFu) * sh;
  g2n[n*2+1] = (float)(unsigned)(g >> 32) * sh;
}

// ---------------------------------------------------------------------------
// Entity feature matrix h_e : [N][288] bf16 (266 real cols + zero pad)
// ---------------------------------------------------------------------------
__global__ void build_he(const float* __restrict__ emb, const float* __restrict__ nte,
                         const float* __restrict__ topic,
                         const float* __restrict__ f1, const float* __restrict__ f2,
                         const float* __restrict__ g1, const float* __restrict__ g2,
                         __hip_bfloat16* __restrict__ He, int N, int nText)
{
  int idx = blockIdx.x * blockDim.x + threadIdx.x;
  if (idx >= N * 288) return;
  int n = idx / 288, j = idx - n * 288;
  float v;
  if (j < 256)      v = (n < nText) ? emb[(size_t)n*256 + j] : nte[j];
  else if (j < 258) v = topic[n*2 + (j-256)];
  else if (j < 260) v = f1[n*2 + (j-258)];
  else if (j < 262) v = f2[n*2 + (j-260)];
  else if (j < 264) v = g1[n*2 + (j-262)];
  else if (j < 266) v = g2[n*2 + (j-264)];
  else              v = 0.0f;
  He[idx] = __float2bfloat16(v);
}

// ---------------------------------------------------------------------------
// Bayesian weight sampling (JAX threefry, partitionable) + fused As packing.
// As[512][288] bf16: row m<256 <- W1[m][256+j]; row 256+m <- W1[m][778+j];
// pad cols 266..287 pre-zeroed by memset (never written here).
// ---------------------------------------------------------------------------
__global__ void sample_kernel(int s,
                              const float* __restrict__ w1_mu, const float* __restrict__ w1_rho,
                              const float* __restrict__ b1_mu, const float* __restrict__ b1_rho,
                              const float* __restrict__ w2_mu, const float* __restrict__ w2_rho,
                              const float* __restrict__ b2_mu, const float* __restrict__ b2_rho,
                              float* __restrict__ W1s, float* __restrict__ b1s,
                              float* __restrict__ w2s, float* __restrict__ b2s,
                              __hip_bfloat16* __restrict__ As)
{
  const int W1N = 267264;   // 256*1044
  int tid = blockIdx.x * blockDim.x + threadIdx.x;
  unsigned F0, F1;
  tf2x32(0u, 42u, 0u, (unsigned)s, F0, F1);   // fold_in(key(42), s)

  if (tid < W1N) {
    unsigned k0, k1; tf2x32(F0, F1, 0u, 0u, k0, k1);              // sk0
    unsigned o0, o1; tf2x32(k0, k1, 0u, (unsigned)tid, o0, o1);
    float w = fmaf(rng_normal(o0 ^ o1), softplusf(w1_rho[tid]), w1_mu[tid]);
    W1s[tid] = w;
    int m = tid / 1044, j = tid - m * 1044;
    if (j >= 256 && j < 522)      As[m * 288 + (j - 256)]         = __float2bfloat16(w);
    else if (j >= 778)            As[(256 + m) * 288 + (j - 778)] = __float2bfloat16(w);
  } else if (tid < W1N + 256) {
    int m = tid - W1N;
    unsigned k0, k1; tf2x32(F0, F1, 0u, 1u, k0, k1);              // sk1
    unsigned o0, o1; tf2x32(k0, k1, 0u, (unsigned)m, o0, o1);
    b1s[m] = fmaf(rng_normal(o0 ^ o1), softplusf(b1_rho[m]), b1_mu[m]);
  } else if (tid < W1N + 512) {
    int m = tid - (W1N + 256);
    unsigned k0, k1; tf2x32(F0, F1, 0u, 2u, k0, k1);              // sk2
    unsigned o0, o1; tf2x32(k0, k1, 0u, (unsigned)m, o0, o1);
    w2s[m] = fmaf(rng_normal(o0 ^ o1), softplusf(w2_rho[m]), w2_mu[m]);
  } else if (tid == W1N + 512) {
    unsigned k0, k1; tf2x32(F0, F1, 0u, 3u, k0, k1);              // sk3
    unsigned o0, o1; tf2x32(k0, k1, 0u, 0u, o0, o1);
    b2s[0] = fmaf(rng_normal(o0 ^ o1), softplusf(b2_rho[0]), b2_mu[0]);
  }
}

// ---------------------------------------------------------------------------
// Fused c + Ar kernel.
// blocks [0, NR): Ar[r][k] = sum_j W1s[k][522+j] * rel[r][j]
// blocks [NR, NR+64): c[k] = b1s[k] + sum_j W1s[k][j] * q[j], wave per k
// ---------------------------------------------------------------------------
__global__ void car_kernel(const float* __restrict__ W1s, const float* __restrict__ b1s,
                           const float* __restrict__ q, const float* __restrict__ rel,
                           float* __restrict__ cvec, float* __restrict__ Ar, int NR)
{
  if ((int)blockIdx.x < NR) {
    __shared__ float rsh[256];
    int r = blockIdx.x, k = threadIdx.x;
    rsh[k] = rel[(size_t)r*256 + k];
    __syncthreads();
    float acc = 0.0f;
    for (int j = 0; j < 256; ++j) acc = fmaf(W1s[k*1044 + 522 + j], rsh[j], acc);
    Ar[(size_t)r*256 + k] = acc;
  } else {
    int k = (blockIdx.x - NR) * 4 + (threadIdx.x >> 6);
    int lane = threadIdx.x & 63;
    float4 v  = *reinterpret_cast<const float4*>(&W1s[(size_t)k * 1044 + lane * 4]);
    float4 qv = *reinterpret_cast<const float4*>(&q[lane * 4]);
    float acc = v.x*qv.x + v.y*qv.y + v.z*qv.z + v.w*qv.w;
    #pragma unroll
    for (int off = 32; off >= 1; off >>= 1) acc += __shfl_down(acc, off, 64);
    if (lane == 0) cvec[k] = acc + b1s[k];
  }
}

// ---------------------------------------------------------------------------
// MFMA GEMM v3 (unchanged from r5): 128x128 tile, BK=32, double-buffered LDS
// via global_load_lds w16, 4-way-max XOR swizzle (source-side pre-swizzle).
// ---------------------------------------------------------------------------
__global__ __launch_bounds__(256) void gemm_mfma(const __hip_bfloat16* __restrict__ Heb,
                                                 const __hip_bfloat16* __restrict__ Asb,
                                                 __hip_bfloat16* __restrict__ U, int nEnt)
{
  __shared__ short lA[2][4096];
  __shared__ short lB[2][4096];

  const int tid  = threadIdx.x;
  const int lane = tid & 63;
  const int wid  = tid >> 6;
  const int wr   = wid >> 1;
  const int wc   = wid & 1;
  const int m0   = blockIdx.x * 128;
  const int n0   = blockIdx.y * 128;
  const short* He = (const short*)Heb;
  const short* As = (const short*)Asb;

  const int lr  = lane & 15;
  const int kb  = (lane >> 4) * 16;
  const int swz = (lane & 3) << 4;

  const int g0row = tid >> 2,  g0c = tid & 3;
  const int g1row = (tid + 256) >> 2;
  const int maxA = nEnt - n0 - 1;
  const int a0r = g0row <= maxA ? g0row : maxA;
  const int a1r = g1row <= maxA ? g1row : maxA;
  const size_t aoff0 = (size_t)a0r * 288 + (g0c ^ (g0row & 3)) * 8;
  const size_t aoff1 = (size_t)a1r * 288 + (g0c ^ (g1row & 3)) * 8;
  const size_t boff0 = (size_t)g0row * 288 + (g0c ^ (g0row & 3)) * 8;
  const size_t boff1 = (size_t)g1row * 288 + (g0c ^ (g1row & 3)) * 8;
  const short* gA = He + (size_t)n0 * 288;
  const short* gB = As + (size_t)m0 * 288;

  #define STAGE(buf, k0)                                              \
    { GLOAD16(gA + (k0) + aoff0, (char*)lA[buf] + tid * 16);          \
      GLOAD16(gA + (k0) + aoff1, (char*)lA[buf] + tid * 16 + 4096);   \
      GLOAD16(gB + (k0) + boff0, (char*)lB[buf] + tid * 16);          \
      GLOAD16(gB + (k0) + boff1, (char*)lB[buf] + tid * 16 + 4096); }

  f32x4 acc[4][4] = {};

  STAGE(0, 0)
  __syncthreads();

  #pragma unroll 1
  for (int ks = 0; ks < 9; ++ks) {
    const int cur = ks & 1;
    if (ks < 8) STAGE(cur ^ 1, (ks + 1) * 32)

    short8 a[4], b[4];
    #pragma unroll
    for (int i = 0; i < 4; ++i) {
      int rowA = wr * 64 + i * 16 + lr;
      a[i] = *reinterpret_cast<const short8*>((const char*)lA[cur] + rowA * 64 + (kb ^ swz));
      int rowB = wc * 64 + i * 16 + lr;
      b[i] = *reinterpret_cast<const short8*>((const char*)lB[cur] + rowB * 64 + (kb ^ swz));
    }
    #pragma unroll
    for (int i = 0; i < 4; ++i)
      #pragma unroll
      for (int j = 0; j < 4; ++j)
        acc[i][j] = __builtin_amdgcn_mfma_f32_16x16x32_bf16(a[i], b[j], acc[i][j], 0, 0, 0);

    __syncthreads();
  }
  #undef STAGE

  const int rg = (lane >> 4) * 4;
  #pragma unroll
  for (int i = 0; i < 4; ++i) {
    #pragma unroll
    for (int r = 0; r < 4; ++r) {
      int n = n0 + wr * 64 + i * 16 + rg + r;
      if (n < nEnt) {
        #pragma unroll
        for (int j = 0; j < 4; ++j)
          U[(size_t)n * 512 + m0 + wc * 64 + j * 16 + lr] = __float2bfloat16(acc[i][j][r]);
      }
    }
  }
}

// ---------------------------------------------------------------------------
// Edge pass: 32 lanes per edge, 8 m-values per lane (bf16 U rows).
// ---------------------------------------------------------------------------
__global__ __launch_bounds__(256) void edge_kernel(const int* __restrict__ h,
                                                   const int* __restrict__ t,
                                                   const int* __restrict__ r,
                                                   const __hip_bfloat16* __restrict__ U,
                                                   const float* __restrict__ Ar,
                                                   const float* __restrict__ cvec,
                                                   const float* __restrict__ w2s,
                                                   const float* __restrict__ b2s,
                                                   float* __restrict__ out, int E, int mode)
{
  int e = blockIdx.x * 8 + (threadIdx.x >> 5);
  int l = threadIdx.x & 31;
  if (e >= E) return;
  int hh = h[e], tt = t[e], rr = r[e];
  const ushort* Ub = (const ushort*)U;

  uint4 uhv = *reinterpret_cast<const uint4*>(Ub + (size_t)hh * 512 + l * 8);
  uint4 utv = *reinterpret_cast<const uint4*>(Ub + (size_t)tt * 512 + 256 + l * 8);
  float4 ar0 = *reinterpret_cast<const float4*>(&Ar[(size_t)rr * 256 + l * 8]);
  float4 ar1 = *reinterpret_cast<const float4*>(&Ar[(size_t)rr * 256 + l * 8 + 4]);
  float4 c0  = *reinterpret_cast<const float4*>(&cvec[l * 8]);
  float4 c1  = *reinterpret_cast<const float4*>(&cvec[l * 8 + 4]);
  float4 w0  = *reinterpret_cast<const float4*>(&w2s[l * 8]);
  float4 w1  = *reinterpret_cast<const float4*>(&w2s[l * 8 + 4]);

  float uh[8], ut[8];
  uh[0] = __uint_as_float(uhv.x << 16); uh[1] = __uint_as_float(uhv.x & 0xFFFF0000u);
  uh[2] = __uint_as_float(uhv.y << 16); uh[3] = __uint_as_float(uhv.y & 0xFFFF0000u);
  uh[4] = __uint_as_float(uhv.z << 16); uh[5] = __uint_as_float(uhv.z & 0xFFFF0000u);
  uh[6] = __uint_as_float(uhv.w << 16); uh[7] = __uint_as_float(uhv.w & 0xFFFF0000u);
  ut[0] = __uint_as_float(utv.x << 16); ut[1] = __uint_as_float(utv.x & 0xFFFF0000u);
  ut[2] = __uint_as_float(utv.y << 16); ut[3] = __uint_as_float(utv.y & 0xFFFF0000u);
  ut[4] = __uint_as_float(utv.z << 16); ut[5] = __uint_as_float(utv.z & 0xFFFF0000u);
  ut[6] = __uint_as_float(utv.w << 16); ut[7] = __uint_as_float(utv.w & 0xFFFF0000u);

  const float cc[8] = {c0.x, c0.y, c0.z, c0.w, c1.x, c1.y, c1.z, c1.w};
  const float aa[8] = {ar0.x, ar0.y, ar0.z, ar0.w, ar1.x, ar1.y, ar1.z, ar1.w};
  const float ww[8] = {w0.x, w0.y, w0.z, w0.w, w1.x, w1.y, w1.z, w1.w};

  float sum = 0.0f;
  #pragma unroll
  for (int i = 0; i < 8; ++i)
    sum += ww[i] * fmaxf(cc[i] + uh[i] + aa[i] + ut[i], 0.0f);

  #pragma unroll
  for (int off = 16; off >= 1; off >>= 1) sum += __shfl_down(sum, off, 32);

  if (l == 0) {
    float v = sum + b2s[0];
    if (mode == 0)      out[e] = v;
    else if (mode == 1) out[e] += v;
    else                out[e] = (out[e] + v) * 0.2f;
  }
}

// ---------------------------------------------------------------------------
// Host launcher
// ---------------------------------------------------------------------------
extern "C" void kernel_launch(void* const* d_in, const int* in_sizes, int n_in,
                              void* d_out, int out_size, void* d_ws, size_t ws_size,
                              hipStream_t stream)
{
  const int*   h_id  = (const int*)  d_in[0];
  const int*   r_id  = (const int*)  d_in[1];
  const int*   t_id  = (const int*)  d_in[2];
  const float* q     = (const float*)d_in[3];
  const float* emb   = (const float*)d_in[4];
  const float* rel   = (const float*)d_in[6];
  const float* topic = (const float*)d_in[7];
  const float* nte   = (const float*)d_in[8];
  const float* w1_mu = (const float*)d_in[9];
  const float* w1_rho= (const float*)d_in[10];
  const float* b1_mu = (const float*)d_in[11];
  const float* b1_rho= (const float*)d_in[12];
  const float* w2_mu = (const float*)d_in[13];
  const float* w2_rho= (const float*)d_in[14];
  const float* b2_mu = (const float*)d_in[15];
  const float* b2_rho= (const float*)d_in[16];

  const int E     = in_sizes[0];
  const int nText = in_sizes[4] / 256;
  const int N     = in_sizes[7] / 2;
  const int NR    = in_sizes[6] / 256;
  float* out = (float*)d_out;

  char* ws = (char*)d_ws;
  size_t off = 0;
  auto alloc = [&](size_t bytes) -> void* {
    void* p = (void*)(ws + off);
    off += (bytes + 255) & ~(size_t)255;
    return p;
  };
  __hip_bfloat16* He  = (__hip_bfloat16*)alloc((size_t)N * 288 * 2);
  __hip_bfloat16* U   = (__hip_bfloat16*)alloc((size_t)N * 512 * 2);
  float* W1s  = (float*)alloc(267264 * 4);
  float* b1s  = (float*)alloc(256 * 4);
  float* w2s  = (float*)alloc(256 * 4);
  float* b2s  = (float*)alloc(64 * 4);
  float* cvec = (float*)alloc(256 * 4);
  float* Ar   = (float*)alloc((size_t)NR * 256 * 4);
  float* f1n  = (float*)alloc((size_t)2 * N * 4);
  float* f2n  = (float*)alloc((size_t)2 * N * 4);
  float* g1n  = (float*)alloc((size_t)2 * N * 4);
  float* g2n  = (float*)alloc((size_t)2 * N * 4);
  // zero-init region: As (pad cols must stay 0) + packed DDE accumulators
  __hip_bfloat16* As = (__hip_bfloat16*)alloc(512 * 288 * 2);
  u64*      Axc_t = (u64*)alloc((size_t)N * 8);
  u64*      Axc_h = (u64*)alloc((size_t)N * 8);
  u64*      F2_t  = (u64*)alloc((size_t)N * 8);
  u64*      G2_h  = (u64*)alloc((size_t)N * 8);
  unsigned* Ay_t  = (unsigned*)alloc((size_t)N * 4);
  unsigned* Ay_h  = (unsigned*)alloc((size_t)N * 4);

  size_t zero_bytes = (size_t)((char*)(Ay_h + N) - (char*)As);
  hipMemsetAsync(As, 0, zero_bytes, stream);

  int eb = (E + 255) / 256;
  int nb = (N + 255) / 256;
  dde_pass1<<<eb, 256, 0, stream>>>(h_id, t_id, topic, Axc_t, Ay_t, Axc_h, Ay_h, E);
  dde_norm1<<<nb, 256, 0, stream>>>(Axc_t, Ay_t, Axc_h, Ay_h, f1n, g1n, N);
  dde_pass2<<<eb, 256, 0, stream>>>(h_id, t_id, f1n, g1n, F2_t, G2_h, E);
  dde_norm2<<<nb, 256, 0, stream>>>(F2_t, G2_h, Axc_t, Axc_h, f2n, g2n, N);

  int heb = ((int)((size_t)N * 288) + 255) / 256;
  build_he<<<heb, 256, 0, stream>>>(emb, nte, topic, f1n, f2n, g1n, g2n, He, N, nText);

  dim3 ggrid(4, (N + 127) / 128);
  for (int s = 0; s < 5; ++s) {
    sample_kernel<<<(267264 + 513 + 255) / 256, 256, 0, stream>>>(
        s, w1_mu, w1_rho, b1_mu, b1_rho, w2_mu, w2_rho, b2_mu, b2_rho,
        W1s, b1s, w2s, b2s, As);
    car_kernel<<<NR + 64, 256, 0, stream>>>(W1s, b1s, q, rel, cvec, Ar, NR);
    gemm_mfma <<<ggrid, 256, 0, stream>>>(He, As, U, N);
    int mode = (s == 0) ? 0 : ((s == 4) ? 2 : 1);
    edge_kernel<<<(E + 7) / 8, 256, 0, stream>>>(h_id, t_id, r_id, U, Ar, cvec,
                                                 w2s, b2s, out, E, mode);
  }
  (void)n_in; (void)out_size; (void)ws_size;
}

// Round 7
// 970.778 us; speedup vs baseline: 1.8138x; 1.2088x over previous
//
#include <hip/hip_runtime.h>
#include <hip/hip_bf16.h>

typedef __attribute__((ext_vector_type(8))) short short8;
typedef __attribute__((ext_vector_type(4))) float f32x4;
typedef unsigned long long u64;

#define GLOAD16(g, l) __builtin_amdgcn_global_load_lds( \
    (const __attribute__((address_space(1))) void*)(g), \
    (__attribute__((address_space(3))) void*)(l), 16, 0, 0)

#define F18 262144.0f            // 2^18 pass1 fixed-point scale
#define F18I (1.0f / 262144.0f)
#define F20 1048576.0f           // 2^20 pass2 fixed-point scale
#define F20I (1.0f / 1048576.0f)

// ---------------------------------------------------------------------------
// Threefry2x32 (JAX partitionable semantics) + erfinv (XLA f32 polynomial)
// ---------------------------------------------------------------------------
#define TF_ROUND(r) { x0 += x1; x1 = ((x1<<(r))|(x1>>(32-(r)))); x1 ^= x0; }

__device__ __forceinline__ void tf2x32(unsigned k0, unsigned k1, unsigned x0, unsigned x1,
                                       unsigned &o0, unsigned &o1)
{
  unsigned ks2 = k0 ^ k1 ^ 0x1BD11BDAu;
  x0 += k0; x1 += k1;
  TF_ROUND(13) TF_ROUND(15) TF_ROUND(26) TF_ROUND(6)
  x0 += k1;  x1 += ks2 + 1u;
  TF_ROUND(17) TF_ROUND(29) TF_ROUND(16) TF_ROUND(24)
  x0 += ks2; x1 += k0 + 2u;
  TF_ROUND(13) TF_ROUND(15) TF_ROUND(26) TF_ROUND(6)
  x0 += k0;  x1 += k1 + 3u;
  TF_ROUND(17) TF_ROUND(29) TF_ROUND(16) TF_ROUND(24)
  x0 += k1;  x1 += ks2 + 4u;
  TF_ROUND(13) TF_ROUND(15) TF_ROUND(26) TF_ROUND(6)
  x0 += ks2; x1 += k0 + 5u;
  o0 = x0; o1 = x1;
}

__device__ __forceinline__ float erfinv_f(float x)
{
  float w = -log1pf(-x * x);
  float p;
  if (w < 5.0f) {
    w -= 2.5f;
    p = 2.81022636e-08f;
    p = fmaf(p, w, 3.43273939e-07f);
    p = fmaf(p, w, -3.5233877e-06f);
    p = fmaf(p, w, -4.39150654e-06f);
    p = fmaf(p, w, 0.00021858087f);
    p = fmaf(p, w, -0.00125372503f);
    p = fmaf(p, w, -0.00417768164f);
    p = fmaf(p, w, 0.246640727f);
    p = fmaf(p, w, 1.50140941f);
  } else {
    w = sqrtf(w) - 3.0f;
    p = -0.000200214257f;
    p = fmaf(p, w, 0.000100950558f);
    p = fmaf(p, w, 0.00134934322f);
    p = fmaf(p, w, -0.00367342844f);
    p = fmaf(p, w, 0.00573950773f);
    p = fmaf(p, w, -0.0076224613f);
    p = fmaf(p, w, 0.00943887047f);
    p = fmaf(p, w, 1.00167406f);
    p = fmaf(p, w, 2.83297682f);
  }
  return p * x;
}

__device__ __forceinline__ float rng_normal(unsigned b)
{
  float f = __uint_as_float((b >> 9) | 0x3f800000u) - 1.0f;  // [0,1)
  const float lo = -0.99999994f;
  float u = fmaxf(lo, f * 2.0f + lo);
  return 1.41421356f * erfinv_f(u);
}

__device__ __forceinline__ float softplusf(float x) { return log1pf(expf(x)); }

// ---------------------------------------------------------------------------
// DDE — packed fixed-point atomics.
// pass1: ONE u64 per direction: [count:12][y:26][x:26] at 2^18 scale.
// pass2: ONE u64 per direction: [y:32][x:32] at 2^20 scale.
// ---------------------------------------------------------------------------
__global__ void dde_pass1(const int* __restrict__ h, const int* __restrict__ t,
                          const float* __restrict__ topic,
                          u64* __restrict__ P1t, u64* __restrict__ P1h, int E)
{
  int e = blockIdx.x * blockDim.x + threadIdx.x;
  if (e >= E) return;
  int hh = h[e], tt = t[e];
  float2 th = *reinterpret_cast<const float2*>(&topic[hh * 2]);
  float2 tv = *reinterpret_cast<const float2*>(&topic[tt * 2]);
  u64 vt = (1ULL << 52) | ((u64)(unsigned)(th.y * F18 + 0.5f) << 26) | (unsigned)(th.x * F18 + 0.5f);
  u64 vh = (1ULL << 52) | ((u64)(unsigned)(tv.y * F18 + 0.5f) << 26) | (unsigned)(tv.x * F18 + 0.5f);
  atomicAdd(&P1t[tt], vt);
  atomicAdd(&P1h[hh], vh);
}

__global__ void dde_norm1(const u64* __restrict__ P1t, const u64* __restrict__ P1h,
                          float* __restrict__ f1n, float* __restrict__ g1n, int N)
{
  int n = blockIdx.x * blockDim.x + threadIdx.x;
  if (n >= N) return;
  u64 pt = P1t[n];
  float st = F18I / fmaxf((float)(unsigned)(pt >> 52), 1.0f);
  f1n[n*2+0] = (float)(unsigned)(pt & 0x3FFFFFFu) * st;
  f1n[n*2+1] = (float)(unsigned)((pt >> 26) & 0x3FFFFFFu) * st;
  u64 ph = P1h[n];
  float sh = F18I / fmaxf((float)(unsigned)(ph >> 52), 1.0f);
  g1n[n*2+0] = (float)(unsigned)(ph & 0x3FFFFFFu) * sh;
  g1n[n*2+1] = (float)(unsigned)((ph >> 26) & 0x3FFFFFFu) * sh;
}

__global__ void dde_pass2(const int* __restrict__ h, const int* __restrict__ t,
                          const float* __restrict__ f1n, const float* __restrict__ g1n,
                          u64* __restrict__ F2_t, u64* __restrict__ G2_h, int E)
{
  int e = blockIdx.x * blockDim.x + threadIdx.x;
  if (e >= E) return;
  int hh = h[e], tt = t[e];
  float2 fv = *reinterpret_cast<const float2*>(&f1n[hh * 2]);
  float2 gv = *reinterpret_cast<const float2*>(&g1n[tt * 2]);
  atomicAdd(&F2_t[tt], ((u64)(unsigned)(fv.y * F20 + 0.5f) << 32) | (unsigned)(fv.x * F20 + 0.5f));
  atomicAdd(&G2_h[hh], ((u64)(unsigned)(gv.y * F20 + 0.5f) << 32) | (unsigned)(gv.x * F20 + 0.5f));
}

__global__ void dde_norm2(const u64* __restrict__ F2_t, const u64* __restrict__ G2_h,
                          const u64* __restrict__ P1t, const u64* __restrict__ P1h,
                          float* __restrict__ f2n, float* __restrict__ g2n, int N)
{
  int n = blockIdx.x * blockDim.x + threadIdx.x;
  if (n >= N) return;
  float st = F20I / fmaxf((float)(unsigned)(P1t[n] >> 52), 1.0f);
  u64 f = F2_t[n];
  f2n[n*2+0] = (float)(unsigned)(f & 0xFFFFFFFFu) * st;
  f2n[n*2+1] = (float)(unsigned)(f >> 32) * st;
  float sh = F20I / fmaxf((float)(unsigned)(P1h[n] >> 52), 1.0f);
  u64 g = G2_h[n];
  g2n[n*2+0] = (float)(unsigned)(g & 0xFFFFFFFFu) * sh;
  g2n[n*2+1] = (float)(unsigned)(g >> 32) * sh;
}

// ---------------------------------------------------------------------------
// Entity feature matrix h_e : [N][288] bf16 (266 real cols + zero pad)
// ---------------------------------------------------------------------------
__global__ void build_he(const float* __restrict__ emb, const float* __restrict__ nte,
                         const float* __restrict__ topic,
                         const float* __restrict__ f1, const float* __restrict__ f2,
                         const float* __restrict__ g1, const float* __restrict__ g2,
                         __hip_bfloat16* __restrict__ He, int N, int nText)
{
  int idx = blockIdx.x * blockDim.x + threadIdx.x;
  if (idx >= N * 288) return;
  int n = idx / 288, j = idx - n * 288;
  float v;
  if (j < 256)      v = (n < nText) ? emb[(size_t)n*256 + j] : nte[j];
  else if (j < 258) v = topic[n*2 + (j-256)];
  else if (j < 260) v = f1[n*2 + (j-258)];
  else if (j < 262) v = f2[n*2 + (j-260)];
  else if (j < 264) v = g1[n*2 + (j-262)];
  else if (j < 266) v = g2[n*2 + (j-264)];
  else              v = 0.0f;
  He[idx] = __float2bfloat16(v);
}

// rel -> bf16 (one-time)
__global__ void rel_cvt(const float* __restrict__ rel, __hip_bfloat16* __restrict__ relb, int n)
{
  int i = blockIdx.x * blockDim.x + threadIdx.x;
  if (i < n) relb[i] = __float2bfloat16(rel[i]);
}

// ---------------------------------------------------------------------------
// Bayesian weight sampling (JAX threefry, partitionable) + packing:
//   As [512][288] bf16: rows m<256 <- W1[m][256+j], rows 256+m <- W1[m][778+j]
//   Asr [256][256] bf16: row m <- W1[m][522+j]
// As pad cols 266..287 pre-zeroed by memset.
// ---------------------------------------------------------------------------
__global__ void sample_kernel(int s,
                              const float* __restrict__ w1_mu, const float* __restrict__ w1_rho,
                              const float* __restrict__ b1_mu, const float* __restrict__ b1_rho,
                              const float* __restrict__ w2_mu, const float* __restrict__ w2_rho,
                              const float* __restrict__ b2_mu, const float* __restrict__ b2_rho,
                              float* __restrict__ W1s, float* __restrict__ b1s,
                              float* __restrict__ w2s, float* __restrict__ b2s,
                              __hip_bfloat16* __restrict__ As, __hip_bfloat16* __restrict__ Asr)
{
  const int W1N = 267264;   // 256*1044
  int tid = blockIdx.x * blockDim.x + threadIdx.x;
  unsigned F0, F1;
  tf2x32(0u, 42u, 0u, (unsigned)s, F0, F1);   // fold_in(key(42), s)

  if (tid < W1N) {
    unsigned k0, k1; tf2x32(F0, F1, 0u, 0u, k0, k1);              // sk0
    unsigned o0, o1; tf2x32(k0, k1, 0u, (unsigned)tid, o0, o1);
    float w = fmaf(rng_normal(o0 ^ o1), softplusf(w1_rho[tid]), w1_mu[tid]);
    W1s[tid] = w;
    int m = tid / 1044, j = tid - m * 1044;
    if (j >= 256 && j < 522)      As[m * 288 + (j - 256)]         = __float2bfloat16(w);
    else if (j >= 522 && j < 778) Asr[m * 256 + (j - 522)]        = __float2bfloat16(w);
    else if (j >= 778)            As[(256 + m) * 288 + (j - 778)] = __float2bfloat16(w);
  } else if (tid < W1N + 256) {
    int m = tid - W1N;
    unsigned k0, k1; tf2x32(F0, F1, 0u, 1u, k0, k1);              // sk1
    unsigned o0, o1; tf2x32(k0, k1, 0u, (unsigned)m, o0, o1);
    b1s[m] = fmaf(rng_normal(o0 ^ o1), softplusf(b1_rho[m]), b1_mu[m]);
  } else if (tid < W1N + 512) {
    int m = tid - (W1N + 256);
    unsigned k0, k1; tf2x32(F0, F1, 0u, 2u, k0, k1);              // sk2
    unsigned o0, o1; tf2x32(k0, k1, 0u, (unsigned)m, o0, o1);
    w2s[m] = fmaf(rng_normal(o0 ^ o1), softplusf(w2_rho[m]), w2_mu[m]);
  } else if (tid == W1N + 512) {
    unsigned k0, k1; tf2x32(F0, F1, 0u, 3u, k0, k1);              // sk3
    unsigned o0, o1; tf2x32(k0, k1, 0u, 0u, o0, o1);
    b2s[0] = fmaf(rng_normal(o0 ^ o1), softplusf(b2_rho[0]), b2_mu[0]);
  }
}

// c[k] = b1s[k] + sum_j W1s[k][j] * q[j]  — one wave per k, coalesced (f32)
__global__ void c_kernel(const float* __restrict__ W1s, const float* __restrict__ b1s,
                         const float* __restrict__ q, float* __restrict__ cvec)
{
  int k = blockIdx.x * 4 + (threadIdx.x >> 6);
  int lane = threadIdx.x & 63;
  float4 v  = *reinterpret_cast<const float4*>(&W1s[(size_t)k * 1044 + lane * 4]);
  float4 qv = *reinterpret_cast<const float4*>(&q[lane * 4]);
  float acc = v.x*qv.x + v.y*qv.y + v.z*qv.z + v.w*qv.w;
  #pragma unroll
  for (int off = 32; off >= 1; off >>= 1) acc += __shfl_down(acc, off, 64);
  if (lane == 0) cvec[k] = acc + b1s[k];
}

// ---------------------------------------------------------------------------
// Ar[r][k] = sum_j rel[r][j]*W1[k][522+j] via MFMA: relb x Asr^T.
// Tiny GEMM M=NR(500) N=256 K=256; all operands L2-hot; no LDS.
// Grid (2 k-tiles, 4 r-tiles) x 256 threads (4 waves, each 64x64).
// Output Arb [NR][256] bf16.
// ---------------------------------------------------------------------------
__global__ __launch_bounds__(256) void ar_mfma(const __hip_bfloat16* __restrict__ relb_,
                                               const __hip_bfloat16* __restrict__ Asr_,
                                               __hip_bfloat16* __restrict__ Arb, int NRr)
{
  const int lane = threadIdx.x & 63;
  const int wid  = threadIdx.x >> 6;
  const int wr = wid >> 1, wc = wid & 1;
  const int r0 = blockIdx.y * 128 + wr * 64;
  const int k0 = blockIdx.x * 128 + wc * 64;
  const int lr = lane & 15, lk = (lane >> 4) * 8;
  const short* A = (const short*)relb_;
  const short* B = (const short*)Asr_;

  const short* pa[4];
  const short* pb[4];
  #pragma unroll
  for (int i = 0; i < 4; ++i) {
    int rr = r0 + i * 16 + lr; if (rr >= NRr) rr = NRr - 1;
    pa[i] = A + (size_t)rr * 256 + lk;
    pb[i] = B + (size_t)(k0 + i * 16 + lr) * 256 + lk;
  }
  f32x4 acc[4][4] = {};
  #pragma unroll
  for (int ks = 0; ks < 8; ++ks) {
    short8 a[4], b[4];
    #pragma unroll
    for (int i = 0; i < 4; ++i) a[i] = *reinterpret_cast<const short8*>(pa[i] + ks * 32);
    #pragma unroll
    for (int j = 0; j < 4; ++j) b[j] = *reinterpret_cast<const short8*>(pb[j] + ks * 32);
    #pragma unroll
    for (int i = 0; i < 4; ++i)
      #pragma unroll
      for (int j = 0; j < 4; ++j)
        acc[i][j] = __builtin_amdgcn_mfma_f32_16x16x32_bf16(a[i], b[j], acc[i][j], 0, 0, 0);
  }
  const int rg = (lane >> 4) * 4;
  #pragma unroll
  for (int i = 0; i < 4; ++i) {
    #pragma unroll
    for (int r_ = 0; r_ < 4; ++r_) {
      int r = r0 + i * 16 + rg + r_;
      if (r < NRr) {
        #pragma unroll
        for (int j = 0; j < 4; ++j)
          Arb[(size_t)r * 256 + k0 + j * 16 + lr] = __float2bfloat16(acc[i][j][r_]);
      }
    }
  }
}

// ---------------------------------------------------------------------------
// MFMA GEMM (unchanged, verified): 128x128 tile, BK=32, dbuf LDS via
// global_load_lds w16, 4-way-max XOR swizzle (source-side pre-swizzle).
// ---------------------------------------------------------------------------
__global__ __launch_bounds__(256) void gemm_mfma(const __hip_bfloat16* __restrict__ Heb,
                                                 const __hip_bfloat16* __restrict__ Asb,
                                                 __hip_bfloat16* __restrict__ U, int nEnt)
{
  __shared__ short lA[2][4096];
  __shared__ short lB[2][4096];

  const int tid  = threadIdx.x;
  const int lane = tid & 63;
  const int wid  = tid >> 6;
  const int wr   = wid >> 1;
  const int wc   = wid & 1;
  const int m0   = blockIdx.x * 128;
  const int n0   = blockIdx.y * 128;
  const short* He = (const short*)Heb;
  const short* As = (const short*)Asb;

  const int lr  = lane & 15;
  const int kb  = (lane >> 4) * 16;
  const int swz = (lane & 3) << 4;

  const int g0row = tid >> 2,  g0c = tid & 3;
  const int g1row = (tid + 256) >> 2;
  const int maxA = nEnt - n0 - 1;
  const int a0r = g0row <= maxA ? g0row : maxA;
  const int a1r = g1row <= maxA ? g1row : maxA;
  const size_t aoff0 = (size_t)a0r * 288 + (g0c ^ (g0row & 3)) * 8;
  const size_t aoff1 = (size_t)a1r * 288 + (g0c ^ (g1row & 3)) * 8;
  const size_t boff0 = (size_t)g0row * 288 + (g0c ^ (g0row & 3)) * 8;
  const size_t boff1 = (size_t)g1row * 288 + (g0c ^ (g1row & 3)) * 8;
  const short* gA = He + (size_t)n0 * 288;
  const short* gB = As + (size_t)m0 * 288;

  #define STAGE(buf, k0)                                              \
    { GLOAD16(gA + (k0) + aoff0, (char*)lA[buf] + tid * 16);          \
      GLOAD16(gA + (k0) + aoff1, (char*)lA[buf] + tid * 16 + 4096);   \
      GLOAD16(gB + (k0) + boff0, (char*)lB[buf] + tid * 16);          \
      GLOAD16(gB + (k0) + boff1, (char*)lB[buf] + tid * 16 + 4096); }

  f32x4 acc[4][4] = {};

  STAGE(0, 0)
  __syncthreads();

  #pragma unroll 1
  for (int ks = 0; ks < 9; ++ks) {
    const int cur = ks & 1;
    if (ks < 8) STAGE(cur ^ 1, (ks + 1) * 32)

    short8 a[4], b[4];
    #pragma unroll
    for (int i = 0; i < 4; ++i) {
      int rowA = wr * 64 + i * 16 + lr;
      a[i] = *reinterpret_cast<const short8*>((const char*)lA[cur] + rowA * 64 + (kb ^ swz));
      int rowB = wc * 64 + i * 16 + lr;
      b[i] = *reinterpret_cast<const short8*>((const char*)lB[cur] + rowB * 64 + (kb ^ swz));
    }
    #pragma unroll
    for (int i = 0; i < 4; ++i)
      #pragma unroll
      for (int j = 0; j < 4; ++j)
        acc[i][j] = __builtin_amdgcn_mfma_f32_16x16x32_bf16(a[i], b[j], acc[i][j], 0, 0, 0);

    __syncthreads();
  }
  #undef STAGE

  const int rg = (lane >> 4) * 4;
  #pragma unroll
  for (int i = 0; i < 4; ++i) {
    #pragma unroll
    for (int r = 0; r < 4; ++r) {
      int n = n0 + wr * 64 + i * 16 + rg + r;
      if (n < nEnt) {
        #pragma unroll
        for (int j = 0; j < 4; ++j)
          U[(size_t)n * 512 + m0 + wc * 64 + j * 16 + lr] = __float2bfloat16(acc[i][j][r]);
      }
    }
  }
}

// ---------------------------------------------------------------------------
// Edge pass: 32 lanes per edge, 8 m-values per lane; U and Ar are bf16.
// ---------------------------------------------------------------------------
__global__ __launch_bounds__(256) void edge_kernel(const int* __restrict__ h,
                                                   const int* __restrict__ t,
                                                   const int* __restrict__ r,
                                                   const __hip_bfloat16* __restrict__ U,
                                                   const __hip_bfloat16* __restrict__ Arb,
                                                   const float* __restrict__ cvec,
                                                   const float* __restrict__ w2s,
                                                   const float* __restrict__ b2s,
                                                   float* __restrict__ out, int E, int mode)
{
  int e = blockIdx.x * 8 + (threadIdx.x >> 5);
  int l = threadIdx.x & 31;
  if (e >= E) return;
  int hh = h[e], tt = t[e], rr = r[e];
  const ushort* Ub = (const ushort*)U;
  const ushort* Ab = (const ushort*)Arb;

  uint4 uhv = *reinterpret_cast<const uint4*>(Ub + (size_t)hh * 512 + l * 8);
  uint4 utv = *reinterpret_cast<const uint4*>(Ub + (size_t)tt * 512 + 256 + l * 8);
  uint4 arv = *reinterpret_cast<const uint4*>(Ab + (size_t)rr * 256 + l * 8);
  float4 c0  = *reinterpret_cast<const float4*>(&cvec[l * 8]);
  float4 c1  = *reinterpret_cast<const float4*>(&cvec[l * 8 + 4]);
  float4 w0  = *reinterpret_cast<const float4*>(&w2s[l * 8]);
  float4 w1  = *reinterpret_cast<const float4*>(&w2s[l * 8 + 4]);

  float uh[8], ut[8], aa[8];
  uh[0] = __uint_as_float(uhv.x << 16); uh[1] = __uint_as_float(uhv.x & 0xFFFF0000u);
  uh[2] = __uint_as_float(uhv.y << 16); uh[3] = __uint_as_float(uhv.y & 0xFFFF0000u);
  uh[4] = __uint_as_float(uhv.z << 16); uh[5] = __uint_as_float(uhv.z & 0xFFFF0000u);
  uh[6] = __uint_as_float(uhv.w << 16); uh[7] = __uint_as_float(uhv.w & 0xFFFF0000u);
  ut[0] = __uint_as_float(utv.x << 16); ut[1] = __uint_as_float(utv.x & 0xFFFF0000u);
  ut[2] = __uint_as_float(utv.y << 16); ut[3] = __uint_as_float(utv.y & 0xFFFF0000u);
  ut[4] = __uint_as_float(utv.z << 16); ut[5] = __uint_as_float(utv.z & 0xFFFF0000u);
  ut[6] = __uint_as_float(utv.w << 16); ut[7] = __uint_as_float(utv.w & 0xFFFF0000u);
  aa[0] = __uint_as_float(arv.x << 16); aa[1] = __uint_as_float(arv.x & 0xFFFF0000u);
  aa[2] = __uint_as_float(arv.y << 16); aa[3] = __uint_as_float(arv.y & 0xFFFF0000u);
  aa[4] = __uint_as_float(arv.z << 16); aa[5] = __uint_as_float(arv.z & 0xFFFF0000u);
  aa[6] = __uint_as_float(arv.w << 16); aa[7] = __uint_as_float(arv.w & 0xFFFF0000u);

  const float cc[8] = {c0.x, c0.y, c0.z, c0.w, c1.x, c1.y, c1.z, c1.w};
  const float ww[8] = {w0.x, w0.y, w0.z, w0.w, w1.x, w1.y, w1.z, w1.w};

  float sum = 0.0f;
  #pragma unroll
  for (int i = 0; i < 8; ++i)
    sum += ww[i] * fmaxf(cc[i] + uh[i] + aa[i] + ut[i], 0.0f);

  #pragma unroll
  for (int off = 16; off >= 1; off >>= 1) sum += __shfl_down(sum, off, 32);

  if (l == 0) {
    float v = sum + b2s[0];
    if (mode == 0)      out[e] = v;
    else if (mode == 1) out[e] += v;
    else                out[e] = (out[e] + v) * 0.2f;
  }
}

// ---------------------------------------------------------------------------
// Host launcher
// ---------------------------------------------------------------------------
extern "C" void kernel_launch(void* const* d_in, const int* in_sizes, int n_in,
                              void* d_out, int out_size, void* d_ws, size_t ws_size,
                              hipStream_t stream)
{
  const int*   h_id  = (const int*)  d_in[0];
  const int*   r_id  = (const int*)  d_in[1];
  const int*   t_id  = (const int*)  d_in[2];
  const float* q     = (const float*)d_in[3];
  const float* emb   = (const float*)d_in[4];
  const float* rel   = (const float*)d_in[6];
  const float* topic = (const float*)d_in[7];
  const float* nte   = (const float*)d_in[8];
  const float* w1_mu = (const float*)d_in[9];
  const float* w1_rho= (const float*)d_in[10];
  const float* b1_mu = (const float*)d_in[11];
  const float* b1_rho= (const float*)d_in[12];
  const float* w2_mu = (const float*)d_in[13];
  const float* w2_rho= (const float*)d_in[14];
  const float* b2_mu = (const float*)d_in[15];
  const float* b2_rho= (const float*)d_in[16];

  const int E     = in_sizes[0];
  const int nText = in_sizes[4] / 256;
  const int N     = in_sizes[7] / 2;
  const int NR    = in_sizes[6] / 256;
  float* out = (float*)d_out;

  char* ws = (char*)d_ws;
  size_t off = 0;
  auto alloc = [&](size_t bytes) -> void* {
    void* p = (void*)(ws + off);
    off += (bytes + 255) & ~(size_t)255;
    return p;
  };
  __hip_bfloat16* He  = (__hip_bfloat16*)alloc((size_t)N * 288 * 2);
  __hip_bfloat16* U   = (__hip_bfloat16*)alloc((size_t)N * 512 * 2);
  __hip_bfloat16* Asr = (__hip_bfloat16*)alloc(256 * 256 * 2);
  __hip_bfloat16* relb= (__hip_bfloat16*)alloc((size_t)NR * 256 * 2);
  __hip_bfloat16* Arb = (__hip_bfloat16*)alloc((size_t)NR * 256 * 2);
  float* W1s  = (float*)alloc(267264 * 4);
  float* b1s  = (float*)alloc(256 * 4);
  float* w2s  = (float*)alloc(256 * 4);
  float* b2s  = (float*)alloc(64 * 4);
  float* cvec = (float*)alloc(256 * 4);
  float* f1n  = (float*)alloc((size_t)2 * N * 4);
  float* f2n  = (float*)alloc((size_t)2 * N * 4);
  float* g1n  = (float*)alloc((size_t)2 * N * 4);
  float* g2n  = (float*)alloc((size_t)2 * N * 4);
  // zero-init region: As pad cols + packed DDE accumulators
  __hip_bfloat16* As = (__hip_bfloat16*)alloc(512 * 288 * 2);
  u64* P1t  = (u64*)alloc((size_t)N * 8);
  u64* P1h  = (u64*)alloc((size_t)N * 8);
  u64* F2_t = (u64*)alloc((size_t)N * 8);
  u64* G2_h = (u64*)alloc((size_t)N * 8);

  size_t zero_bytes = (size_t)((char*)(G2_h + N) - (char*)As);
  hipMemsetAsync(As, 0, zero_bytes, stream);

  int eb = (E + 255) / 256;
  int nb = (N + 255) / 256;
  dde_pass1<<<eb, 256, 0, stream>>>(h_id, t_id, topic, P1t, P1h, E);
  dde_norm1<<<nb, 256, 0, stream>>>(P1t, P1h, f1n, g1n, N);
  dde_pass2<<<eb, 256, 0, stream>>>(h_id, t_id, f1n, g1n, F2_t, G2_h, E);
  dde_norm2<<<nb, 256, 0, stream>>>(F2_t, G2_h, P1t, P1h, f2n, g2n, N);

  int heb = ((int)((size_t)N * 288) + 255) / 256;
  build_he<<<heb, 256, 0, stream>>>(emb, nte, topic, f1n, f2n, g1n, g2n, He, N, nText);
  rel_cvt<<<(NR * 256 + 255) / 256, 256, 0, stream>>>(rel, relb, NR * 256);

  dim3 ggrid(4, (N + 127) / 128);
  dim3 agrid(2, (NR + 127) / 128);
  for (int s = 0; s < 5; ++s) {
    sample_kernel<<<(267264 + 513 + 255) / 256, 256, 0, stream>>>(
        s, w1_mu, w1_rho, b1_mu, b1_rho, w2_mu, w2_rho, b2_mu, b2_rho,
        W1s, b1s, w2s, b2s, As, Asr);
    c_kernel<<<64, 256, 0, stream>>>(W1s, b1s, q, cvec);
    ar_mfma <<<agrid, 256, 0, stream>>>(relb, Asr, Arb, NR);
    gemm_mfma<<<ggrid, 256, 0, stream>>>(He, As, U, N);
    int mode = (s == 0) ? 0 : ((s == 4) ? 2 : 1);
    edge_kernel<<<(E + 7) / 8, 256, 0, stream>>>(h_id, t_id, r_id, U, Arb, cvec,
                                                 w2s, b2s, out, E, mode);
  }
  (void)n_in; (void)out_size; (void)ws_size;
}